// Round 9
// baseline (4985.915 us; speedup 1.0000x reference)
//
#include <hip/hip_runtime.h>
#include <math.h>

constexpr int BATCH = 256;
constexpr int EQ_   = 192;
constexpr int EC_   = 240;
constexpr int EPG   = 432;   // edges per pair
constexpr int NPG   = 216;   // nodes per pair
constexpr int NN    = BATCH * NPG;   // 55296
constexpr int NE    = BATCH * EPG;   // 110592

typedef __attribute__((ext_vector_type(8))) short short8;
typedef __attribute__((ext_vector_type(4))) float floatx4;
typedef unsigned short u16;

__device__ __forceinline__ u16 f2bf(float x) {
  union { float f; unsigned u; } c; c.f = x;
  const unsigned r = (c.u + 0x7FFFu + ((c.u >> 16) & 1u)) >> 16;
  return (u16)r;
}
__device__ __forceinline__ float bf2f(u16 x) {
  union { unsigned u; float f; } c; c.u = ((unsigned)x) << 16;
  return c.f;
}
__device__ __forceinline__ short8 cvt8(const float* __restrict__ p) {
  const float4 a = *(const float4*)p;
  const float4 b = *(const float4*)(p + 4);
  short8 o;
  o[0]=(short)f2bf(a.x); o[1]=(short)f2bf(a.y); o[2]=(short)f2bf(a.z); o[3]=(short)f2bf(a.w);
  o[4]=(short)f2bf(b.x); o[5]=(short)f2bf(b.y); o[6]=(short)f2bf(b.z); o[7]=(short)f2bf(b.w);
  return o;
}

__device__ __forceinline__ void lse_merge(float& m, float& s, float om, float os) {
  const float nm = fmaxf(m, om);
  s = s * __expf(m - nm) + os * __expf(om - nm);
  m = nm;
}
__device__ __forceinline__ void lse_online(float& m, float& s, float tt) {
  if (tt > m) { s = s * __expf(m - tt) + 1.f; m = tt; }
  else        { s += __expf(tt - m); }
}

// ---------------------------------------------------------------------------
// weight transpose + f32->bf16:  out[n*K+k] = bf16(W[k*N+n])
// ---------------------------------------------------------------------------
__global__ __launch_bounds__(256)
void wconv(const float* __restrict__ W, u16* __restrict__ out, int K, int N)
{
  const int i = blockIdx.x * 256 + threadIdx.x;
  if (i < K * N) {
    const int n = i / K, k = i - n * K;
    out[i] = f2bf(W[(size_t)k * N + n]);
  }
}

// ---------------------------------------------------------------------------
// MFMA fused 2-layer MLP, 32-row tiles, LDS union (sA aliases sH).
// (round-6 proven version)
// IN_MODE: 1 [h[IA],h[IB],comb]  3 [h,aggF,aggB]  4 [e, inter(or 0)]
// DUAL: also compute with first two 64-blocks swapped (k^64).
// OUT_MODE: 0 f32 write (sum over dirs)  1 bf16 write (sum)  2 bf16 per-dir -> Yb0/Yb1
// ---------------------------------------------------------------------------
template<int K1, int HID, int NOUT, int IN_MODE, int DUAL, int OUT_MODE>
__global__ __launch_bounds__(256, 4)
void mlp_mfma(const float* __restrict__ X, const float* __restrict__ P2,
              const float* __restrict__ P3, const u16* __restrict__ CB,
              const int* __restrict__ IA, const int* __restrict__ IB,
              const u16* __restrict__ W1t, const float* __restrict__ B1,
              const u16* __restrict__ W2t, const float* __restrict__ B2,
              float* __restrict__ Yf, u16* __restrict__ Yb0, u16* __restrict__ Yb1)
{
  constexpr int RT  = 32;
  constexpr int KCH = K1 / 8;
  constexpr int NT1 = HID / 64;
  constexpr int NT2 = (NOUT >= 64) ? NOUT / 64 : 1;
  constexpr int SAB = RT * K1 * 2;
  constexpr int SHB = RT * (HID + 8) * 2;
  __shared__ __align__(16) char smem[(SAB > SHB ? SAB : SHB)];
  u16* sA = (u16*)smem;
  u16* sH = (u16*)smem;

  const int tid = threadIdx.x;
  const int rowBase = blockIdx.x * RT;

  // ---- stage A panel (gather + cvt), XOR-swizzled rows ----
  for (int ch = tid; ch < RT * KCH; ch += 256) {
    const int r = ch / KCH, kc = ch - r * KCH;
    const int gr = rowBase + r, k0 = kc * 8;
    short8 pk;
    if constexpr (IN_MODE == 4) {
      if (k0 < 128)      pk = cvt8(&X[(size_t)gr * 128 + k0]);
      else if (P2)       pk = cvt8(&P2[(size_t)gr * 128 + (k0 - 128)]);
      else { pk = short8{0,0,0,0,0,0,0,0}; }
    } else if constexpr (IN_MODE == 1) {
      if (k0 < 64)       pk = cvt8(&X[(size_t)IA[gr] * 64 + k0]);
      else if (k0 < 128) pk = cvt8(&X[(size_t)IB[gr] * 64 + (k0 - 64)]);
      else               pk = *(const short8*)&CB[(size_t)gr * 128 + (k0 - 128)];
    } else { // 3
      if (k0 < 64)       pk = cvt8(&X[(size_t)gr * 64 + k0]);
      else if (k0 < 192) pk = cvt8(&P2[(size_t)gr * 128 + (k0 - 64)]);
      else               pk = cvt8(&P3[(size_t)gr * 128 + (k0 - 192)]);
    }
    const int byte = ((r * K1 + k0) * 2) ^ ((r & 7) << 4);
    *(short8*)((char*)sA + byte) = pk;
  }
  __syncthreads();

  const int wid = tid >> 6, lane = tid & 63;
  const int l15 = lane & 15, lg = lane >> 4;

  // ---- layer 1, all dirs (sA stays live only here) ----
  floatx4 acc1[1 + DUAL][2][NT1];
  #pragma unroll
  for (int d = 0; d <= DUAL; ++d)
    #pragma unroll
    for (int m = 0; m < 2; ++m)
      #pragma unroll
      for (int n = 0; n < NT1; ++n) acc1[d][m][n] = floatx4{0.f,0.f,0.f,0.f};

  #pragma unroll 2
  for (int kk = 0; kk < K1 / 32; ++kk) {
    short8 bw[NT1];
    #pragma unroll
    for (int n = 0; n < NT1; ++n) {
      const int col = wid * (HID / 4) + n * 16 + l15;
      bw[n] = *(const short8*)&W1t[(size_t)col * K1 + kk * 32 + lg * 8];
    }
    #pragma unroll
    for (int d = 0; d <= DUAL; ++d) {
      int k0 = kk * 32 + lg * 8;
      if (DUAL && d && k0 < 128) k0 ^= 64;
      #pragma unroll
      for (int m = 0; m < 2; ++m) {
        const int r = m * 16 + l15;
        const int byte = ((r * K1 + k0) * 2) ^ ((r & 7) << 4);
        const short8 af = *(const short8*)((char*)sA + byte);
        #pragma unroll
        for (int n = 0; n < NT1; ++n)
          acc1[d][m][n] = __builtin_amdgcn_mfma_f32_16x16x32_bf16(af, bw[n], acc1[d][m][n], 0, 0, 0);
      }
    }
  }
  __syncthreads();   // sA dead from here; smem becomes sH

  floatx4 accO[2][NT2];
  #pragma unroll
  for (int m = 0; m < 2; ++m)
    #pragma unroll
    for (int n = 0; n < NT2; ++n) accO[m][n] = floatx4{0.f,0.f,0.f,0.f};

  #pragma unroll
  for (int d = 0; d <= DUAL; ++d) {
    // hidden: bias + relu -> bf16 LDS
    #pragma unroll
    for (int n = 0; n < NT1; ++n) {
      const int col = wid * (HID / 4) + n * 16 + l15;
      const float b1 = B1[col];
      #pragma unroll
      for (int m = 0; m < 2; ++m)
        #pragma unroll
        for (int r = 0; r < 4; ++r) {
          const int row = m * 16 + lg * 4 + r;
          const float y = acc1[d][m][n][r] + b1;
          sH[row * (HID + 8) + col] = f2bf(y > 0.f ? y : 0.f);
        }
    }
    __syncthreads();
    if (OUT_MODE == 2 && d == 1) {
      #pragma unroll
      for (int m = 0; m < 2; ++m)
        #pragma unroll
        for (int n = 0; n < NT2; ++n) accO[m][n] = floatx4{0.f,0.f,0.f,0.f};
    }
    #pragma unroll 2
    for (int kk = 0; kk < HID / 32; ++kk) {
      short8 bw2[NT2];
      #pragma unroll
      for (int n = 0; n < NT2; ++n) {
        const int col = wid * (NOUT / 4) + n * 16 + l15;
        bw2[n] = *(const short8*)&W2t[(size_t)col * HID + kk * 32 + lg * 8];
      }
      #pragma unroll
      for (int m = 0; m < 2; ++m) {
        const short8 af = *(const short8*)&sH[(m * 16 + l15) * (HID + 8) + kk * 32 + lg * 8];
        #pragma unroll
        for (int n = 0; n < NT2; ++n)
          accO[m][n] = __builtin_amdgcn_mfma_f32_16x16x32_bf16(af, bw2[n], accO[m][n], 0, 0, 0);
      }
    }
    if constexpr (OUT_MODE == 2) {
      u16* Y = d ? Yb1 : Yb0;
      #pragma unroll
      for (int n = 0; n < NT2; ++n) {
        const int col = wid * (NOUT / 4) + n * 16 + l15;
        const float b2 = B2[col];
        #pragma unroll
        for (int m = 0; m < 2; ++m)
          #pragma unroll
          for (int r = 0; r < 4; ++r) {
            const int gr = rowBase + m * 16 + lg * 4 + r;
            Y[(size_t)gr * NOUT + col] = f2bf(accO[m][n][r] + b2);
          }
      }
    }
    if (DUAL && d == 0) __syncthreads();   // before overwriting sH
  }

  if constexpr (OUT_MODE != 2) {
    #pragma unroll
    for (int n = 0; n < NT2; ++n) {
      const int col = wid * (NOUT / 4) + n * 16 + l15;
      const float b2 = B2[col] * (float)(1 + DUAL);
      #pragma unroll
      for (int m = 0; m < 2; ++m)
        #pragma unroll
        for (int r = 0; r < 4; ++r) {
          const int gr = rowBase + m * 16 + lg * 4 + r;
          const float y = accO[m][n][r] + b2;
          if constexpr (OUT_MODE == 1) Yb0[(size_t)gr * NOUT + col] = f2bf(y);
          else                         Yf[(size_t)gr * NOUT + col] = y;
        }
    }
  }
}

// ---------------------------------------------------------------------------
// Pair-local segment-sum scatter: block = pair*2 + dir.
// ---------------------------------------------------------------------------
__global__ __launch_bounds__(256)
void scatter_agg(const u16* __restrict__ MF, const u16* __restrict__ MB,
                 const int* __restrict__ FI, const int* __restrict__ TI,
                 float* __restrict__ AggF, float* __restrict__ AggB)
{
  const int pair = blockIdx.x >> 1, dir = blockIdx.x & 1;
  const u16* M  = dir ? MB : MF;
  const int* SI = dir ? FI : TI;
  float* Agg    = dir ? AggB : AggF;
  const int tid = threadIdx.x;
  __shared__ float sAgg[NPG * 128];

  for (int i = tid; i < NPG * 128; i += 256) sAgg[i] = 0.f;
  __syncthreads();

  for (int i = tid; i < EPG * 32; i += 256) {
    const int edge = i >> 5, cb = i & 31;
    const int er = pair * EPG + edge;
    const int node = SI[er] - pair * NPG;
    const size_t base = (size_t)er * 128 + cb;
    #pragma unroll
    for (int k = 0; k < 4; ++k)
      atomicAdd(&sAgg[node * 128 + cb + 32 * k], bf2f(M[base + 32 * k]));
  }
  __syncthreads();
  float* dst = Agg + (size_t)pair * NPG * 128;
  for (int i = tid; i < NPG * 128; i += 256) dst[i] = sAgg[i];
}

// ---------------------------------------------------------------------------
// f32 fused MLP (encoders + sinkhorn feature MLPs)
// IN_MODE: 0 plain X  5 q-side rows of e (zero-padded)  6 c-side rows
// ---------------------------------------------------------------------------
template<int K1, int HID, int NOUT, int IN_MODE, int SINGLE>
__global__ __launch_bounds__(256)
void fused_mlp(const float* __restrict__ X, const float* __restrict__ P1,
               const float* __restrict__ W1, const float* __restrict__ B1,
               const float* __restrict__ W2, const float* __restrict__ B2,
               float* __restrict__ Y, int maskLen)
{
  constexpr int RT = 32, BK = 32;
  constexpr int J1 = HID / 32;
  constexpr int J2 = NOUT / 32;
  constexpr int BMAX = (HID > NOUT ? HID : NOUT);
  __shared__ float sA[RT * 33];
  __shared__ float sB[BK * BMAX];
  __shared__ float sH[SINGLE ? 1 : RT * (HID + 1)];

  const int t  = threadIdx.x;
  const int tx = t & 31, ty = t >> 5;
  const int rowBase = blockIdx.x * RT;

  float acc[4][J1];
  #pragma unroll
  for (int i = 0; i < 4; ++i)
    #pragma unroll
    for (int j = 0; j < J1; ++j) acc[i][j] = 0.f;

  for (int kb = 0; kb < K1; kb += BK) {
    for (int l = t; l < RT * BK; l += 256) {
      const int r = l >> 5, k = l & 31;
      const int gr = rowBase + r, gk = kb + k;
      float v;
      if constexpr (IN_MODE == 0) {
        v = X[(size_t)gr * K1 + gk];
      } else {
        const int bb = gr >> 8, m = gr & 255;
        constexpr int off = (IN_MODE == 5) ? 0 : EQ_;
        constexpr int len = (IN_MODE == 5) ? EQ_ : EC_;
        v = (m < len) ? P1[((size_t)bb * EPG + off + m) * 128 + gk] : 0.f;
      }
      sA[r * 33 + k] = v;
    }
    for (int l = t * 4; l < BK * HID; l += 1024) {
      *(float4*)&sB[l] = *(const float4*)&W1[(size_t)(kb + l / HID) * HID + (l % HID)];
    }
    __syncthreads();
    #pragma unroll
    for (int k = 0; k < BK; ++k) {
      const float a0 = sA[(ty*4+0)*33+k], a1 = sA[(ty*4+1)*33+k],
                  a2 = sA[(ty*4+2)*33+k], a3 = sA[(ty*4+3)*33+k];
      #pragma unroll
      for (int j = 0; j < J1; ++j) {
        const float bb = sB[k * HID + tx + 32*j];
        acc[0][j] += a0 * bb; acc[1][j] += a1 * bb;
        acc[2][j] += a2 * bb; acc[3][j] += a3 * bb;
      }
    }
    __syncthreads();
  }

  if constexpr (SINGLE) {
    #pragma unroll
    for (int j = 0; j < J1; ++j) {
      const int col = tx + 32*j;
      const float bias = B1[col];
      #pragma unroll
      for (int i = 0; i < 4; ++i) {
        const int gr = rowBase + ty*4 + i;
        Y[(size_t)gr * HID + col] = acc[i][j] + bias;
      }
    }
  } else {
    #pragma unroll
    for (int j = 0; j < J1; ++j) {
      const int col = tx + 32*j;
      const float bias = B1[col];
      #pragma unroll
      for (int i = 0; i < 4; ++i) {
        float y = acc[i][j] + bias;
        sH[(ty*4+i) * (HID+1) + col] = y > 0.f ? y : 0.f;
      }
    }
    __syncthreads();

    float acc2[4][J2];
    #pragma unroll
    for (int i = 0; i < 4; ++i)
      #pragma unroll
      for (int j = 0; j < J2; ++j) acc2[i][j] = 0.f;

    for (int kb = 0; kb < HID; kb += BK) {
      for (int l = t * 4; l < BK * NOUT; l += 1024) {
        *(float4*)&sB[l] = *(const float4*)&W2[(size_t)(kb + l / NOUT) * NOUT + (l % NOUT)];
      }
      __syncthreads();
      #pragma unroll
      for (int k = 0; k < BK; ++k) {
        const float a0 = sH[(ty*4+0)*(HID+1) + kb + k],
                    a1 = sH[(ty*4+1)*(HID+1) + kb + k],
                    a2 = sH[(ty*4+2)*(HID+1) + kb + k],
                    a3 = sH[(ty*4+3)*(HID+1) + kb + k];
        #pragma unroll
        for (int j = 0; j < J2; ++j) {
          const float bb = sB[k * NOUT + tx + 32*j];
          acc2[0][j] += a0 * bb; acc2[1][j] += a1 * bb;
          acc2[2][j] += a2 * bb; acc2[3][j] += a3 * bb;
        }
      }
      __syncthreads();
    }
    #pragma unroll
    for (int j = 0; j < J2; ++j) {
      const int col = tx + 32*j;
      const float bias = B2[col];
      #pragma unroll
      for (int i = 0; i < 4; ++i) {
        const int gr = rowBase + ty*4 + i;
        float y = acc2[i][j] + bias;
        if (maskLen >= 0 && (gr & 255) >= maskLen) y = 0.f;
        Y[(size_t)gr * NOUT + col] = y;
      }
    }
  }
}

// ---------------------------------------------------------------------------
// S[b] = scale * fq[b] @ fc[b]^T
// ---------------------------------------------------------------------------
__global__ __launch_bounds__(256)
void gemm_nt_scale(const float* __restrict__ A, const float* __restrict__ Bm,
                   float* __restrict__ C, float scale)
{
  const int b = blockIdx.z, qt = blockIdx.x, ct = blockIdx.y;
  __shared__ float sA[64 * 68];
  __shared__ float sB[64 * 68];
  const int t = threadIdx.x;
  const int tx = t & 15, ty = t >> 4;
  const float* Ab = A  + (size_t)b * 16384 + (size_t)qt * 4096;
  const float* Bb = Bm + (size_t)b * 16384 + (size_t)ct * 4096;
  for (int l = t * 4; l < 64 * 64; l += 1024) {
    const int r = l >> 6, d = l & 63;
    *(float4*)&sA[r*68 + d] = *(const float4*)&Ab[r*64 + d];
    *(float4*)&sB[r*68 + d] = *(const float4*)&Bb[r*64 + d];
  }
  __syncthreads();
  float acc[4][4] = {};
  #pragma unroll
  for (int d = 0; d < 64; ++d) {
    float a[4], bb[4];
    #pragma unroll
    for (int i = 0; i < 4; ++i) a[i]  = sA[(ty*4+i)*68 + d];
    #pragma unroll
    for (int j = 0; j < 4; ++j) bb[j] = sB[(tx+16*j)*68 + d];
    #pragma unroll
    for (int i = 0; i < 4; ++i)
      #pragma unroll
      for (int j = 0; j < 4; ++j) acc[i][j] += a[i] * bb[j];
  }
  float* Cb = C + (size_t)b * 65536 + (size_t)(qt*64) * 256 + ct*64;
  #pragma unroll
  for (int i = 0; i < 4; ++i)
    #pragma unroll
    for (int j = 0; j < 4; ++j)
      Cb[(ty*4+i)*256 + tx + 16*j] = acc[i][j] * scale;
}

// ---------------------------------------------------------------------------
// Y rows r<maskRows at ((b*RPB + YOFF + r)*128) = op(P[b]) @ V (gathered from e)
// ---------------------------------------------------------------------------
template<int TRANSA>
__global__ __launch_bounds__(256)
void gemm_plan(const float* __restrict__ P, const float* __restrict__ E,
               float* __restrict__ Y, int RPB, int YOFF, int VOFF, int VLEN,
               int maskRows)
{
  const int b = blockIdx.y, rt = blockIdx.x;
  __shared__ float sA[64 * 33];
  __shared__ float sB[32 * 128];
  const int t = threadIdx.x;
  const int tx = t & 15, ty = t >> 4;
  const float* Pb = P + (size_t)b * 65536;
  float acc[4][8] = {};
  for (int kb = 0; kb < 256; kb += 32) {
    if constexpr (TRANSA == 0) {
      for (int l = t; l < 64 * 32; l += 256) {
        const int r = l >> 5, k = l & 31;
        sA[r*33 + k] = Pb[(size_t)(rt*64 + r) * 256 + kb + k];
      }
    } else {
      for (int l = t; l < 64 * 32; l += 256) {
        const int r = l & 63, k = l >> 6;
        sA[r*33 + k] = Pb[(size_t)(kb + k) * 256 + rt*64 + r];
      }
    }
    for (int l = t * 4; l < 32 * 128; l += 1024) {
      const int vr = kb + (l >> 7), d = l & 127;
      float4 val = {0.f, 0.f, 0.f, 0.f};
      if (vr < VLEN) val = *(const float4*)&E[((size_t)b * EPG + VOFF + vr) * 128 + d];
      *(float4*)&sB[l] = val;
    }
    __syncthreads();
    #pragma unroll
    for (int k = 0; k < 32; ++k) {
      float a[4], bb[8];
      #pragma unroll
      for (int i = 0; i < 4; ++i) a[i]  = sA[(ty*4+i)*33 + k];
      #pragma unroll
      for (int j = 0; j < 8; ++j) bb[j] = sB[k*128 + tx + 16*j];
      #pragma unroll
      for (int i = 0; i < 4; ++i)
        #pragma unroll
        for (int j = 0; j < 8; ++j) acc[i][j] += a[i] * bb[j];
    }
    __syncthreads();
  }
  #pragma unroll
  for (int i = 0; i < 4; ++i) {
    const int r = rt*64 + ty*4 + i;
    if (r >= maskRows) continue;
    float* yr = Y + ((size_t)b * RPB + YOFF + r) * 128;
    #pragma unroll
    for (int j = 0; j < 8; ++j) yr[tx + 16*j] = acc[i][j];
  }
}

// ---------------------------------------------------------------------------
// Register-resident fused sinkhorn: block = pair, 1024 threads.
// amdgpu_waves_per_eu(4,4): the backend honors this function attribute for
// the register budget (512/4 = 128 VGPR), unlike __launch_bounds__'s second
// arg which this toolchain ignores (evidence: r3 mlp compiled to 176 VGPR
// under (256,4); r8 sinkhorn stayed at 64 VGPR under (1024,4)).
// Need ~104 VGPR (sreg 64 + ureg 16 + vreg 4 + col partials 8 + temps) -> no
// spill. S is read ONCE and written ONCE; all 10 iterations run in registers.
// ---------------------------------------------------------------------------
__global__ __launch_bounds__(1024)
__attribute__((amdgpu_waves_per_eu(4, 4)))
void sinkhorn_fused(float* __restrict__ S)
{
  const int b = blockIdx.x, t = threadIdx.x;
  float* Sb = S + (size_t)b * 65536;
  const int w = t >> 6, lane = t & 63;
  const int cbase = lane * 4;
  __shared__ float pm[16 * 256], ps[16 * 256];
  __shared__ float sv[256];

  float4 sreg[16];
  #pragma unroll
  for (int i = 0; i < 16; ++i)
    sreg[i] = *(const float4*)&Sb[(size_t)(w * 16 + i) * 256 + cbase];

  float4 vreg = {0.f, 0.f, 0.f, 0.f};
  float ureg[16];

  for (int it = 0; it < 10; ++it) {
    // row pass: u[r] = -LSE_c(S[r,c] + v[c]); butterfly leaves result in all lanes
    #pragma unroll
    for (int i = 0; i < 16; ++i) {
      float m = -1e30f, s = 0.f;
      lse_online(m, s, sreg[i].x + vreg.x);
      lse_online(m, s, sreg[i].y + vreg.y);
      lse_online(m, s, sreg[i].z + vreg.z);
      lse_online(m, s, sreg[i].w + vreg.w);
      #pragma unroll
      for (int off = 32; off; off >>= 1) {
        const float om = __shfl_xor(m, off);
        const float os = __shfl_xor(s, off);
        lse_merge(m, s, om, os);
      }
      ureg[i] = -(m + __logf(s));
    }
    // col partials over this wave's 16 rows (pure registers)
    float4 cm = {-1e30f, -1e30f, -1e30f, -1e30f};
    float4 cs = {0.f, 0.f, 0.f, 0.f};
    #pragma unroll
    for (int i = 0; i < 16; ++i) {
      lse_online(cm.x, cs.x, sreg[i].x + ureg[i]);
      lse_online(cm.y, cs.y, sreg[i].y + ureg[i]);
      lse_online(cm.z, cs.z, sreg[i].z + ureg[i]);
      lse_online(cm.w, cs.w, sreg[i].w + ureg[i]);
    }
    *(float4*)&pm[w * 256 + cbase] = cm;
    *(float4*)&ps[w * 256 + cbase] = cs;
    __syncthreads();
    if (t < 256) {
      float m = pm[t], s = ps[t];
      #pragma unroll
      for (int k = 1; k < 16; ++k)
        lse_merge(m, s, pm[k * 256 + t], ps[k * 256 + t]);
      sv[t] = -(m + __logf(s));
    }
    __syncthreads();
    vreg = *(const float4*)&sv[cbase];
  }
  // planify: S := exp(S + u + v), write once
  #pragma unroll
  for (int i = 0; i < 16; ++i) {
    float4 o;
    o.x = __expf(sreg[i].x + ureg[i] + vreg.x);
    o.y = __expf(sreg[i].y + ureg[i] + vreg.y);
    o.z = __expf(sreg[i].z + ureg[i] + vreg.z);
    o.w = __expf(sreg[i].w + ureg[i] + vreg.w);
    *(float4*)&Sb[(size_t)(w * 16 + i) * 256 + cbase] = o;
  }
}

// ---------------------------------------------------------------------------
// score[b] = -sum_{m<256,d} | (m<EQ ? e_q[m,d] : 0) - pc[m,d] |
// ---------------------------------------------------------------------------
__global__ __launch_bounds__(256)
void escore_kernel(const float* __restrict__ e, const float* __restrict__ pc,
                   float* __restrict__ out)
{
  const int b = blockIdx.x, t = threadIdx.x;
  float acc = 0.f;
  for (int i4 = t; i4 < 8192; i4 += 256) {
    const int flat = i4 * 4;
    const int m = flat >> 7, d = flat & 127;
    float4 p = *(const float4*)&pc[((size_t)b * 256 + m) * 128 + d];
    float4 q = {0.f, 0.f, 0.f, 0.f};
    if (m < EQ_) q = *(const float4*)&e[((size_t)b * EPG + m) * 128 + d];
    acc += fabsf(q.x - p.x) + fabsf(q.y - p.y) + fabsf(q.z - p.z) + fabsf(q.w - p.w);
  }
  __shared__ float red[256];
  red[t] = acc; __syncthreads();
  for (int s2 = 128; s2 > 0; s2 >>= 1) { if (t < s2) red[t] += red[t + s2]; __syncthreads(); }
  if (t == 0) out[b] = -red[0];
}

// ---------------------------------------------------------------------------
extern "C" void kernel_launch(void* const* d_in, const int* in_sizes, int n_in,
                              void* d_out, int out_size, void* d_ws, size_t ws_size,
                              hipStream_t stream)
{
  const float* node_features = (const float*)d_in[0];
  const float* edge_features = (const float*)d_in[1];
  const int*   from_idx      = (const int*)d_in[2];
  const int*   to_idx        = (const int*)d_in[3];
  const float* enc_node_W = (const float*)d_in[4];
  const float* enc_node_b = (const float*)d_in[5];
  const float* enc_edge_W = (const float*)d_in[6];
  const float* enc_edge_b = (const float*)d_in[7];
  const float* msg_W1 = (const float*)d_in[8];
  const float* msg_b1 = (const float*)d_in[9];
  const float* msg_W2 = (const float*)d_in[10];
  const float* msg_b2 = (const float*)d_in[11];
  const float* upd_W1 = (const float*)d_in[12];
  const float* upd_b1 = (const float*)d_in[13];
  const float* upd_W2 = (const float*)d_in[14];
  const float* upd_b2 = (const float*)d_in[15];
  const float* int_W1 = (const float*)d_in[16];
  const float* int_b1 = (const float*)d_in[17];
  const float* int_W2 = (const float*)d_in[18];
  const float* int_b2 = (const float*)d_in[19];
  const float* sink_W1 = (const float*)d_in[20];
  const float* sink_b1 = (const float*)d_in[21];
  const float* sink_W2 = (const float*)d_in[22];
  const float* sink_b2 = (const float*)d_in[23];
  float* out = (float*)d_out;

  // ~224 MB layout (round-3/5/6/8 proven). mf/mb bf16 alias e's dead window.
  float* wsf = (float*)d_ws;
  float* h   = wsf;                               // NN*64 f32
  float* e   = h + (size_t)NN * 64;               // NE*128 f32
  float* shr = e + (size_t)NE * 128;              // NE*128 f32 (inter | aggF+aggB | fq+fc | pc)
  float* S   = shr + (size_t)NE * 128;            // BATCH*65536 f32
  u16* comb  = (u16*)(S + (size_t)BATCH * 65536); // NE*128 bf16
  u16* wi1 = comb + (size_t)NE * 128;             // 256x256
  u16* wi2 = wi1 + 65536;                         // 128x256
  u16* wm1 = wi2 + 32768;                         // 256x256
  u16* wm2 = wm1 + 65536;                         // 128x256
  u16* wu1 = wm2 + 32768;                         // 128x320
  u16* wu2 = wu1 + 40960;                         // 64x128

  u16* mfb = (u16*)e;                             // aliases e (dead window)
  u16* mbb = mfb + (size_t)NE * 128;

  float* aggF  = shr;
  float* aggB  = shr + (size_t)NN * 128;
  float* inter = shr;                             // EPG-row layout
  float* fq    = shr;
  float* fc    = shr + (size_t)BATCH * 16384;

  // weights -> bf16, transposed [N][K]
  wconv<<<256, 256, 0, stream>>>(int_W1, wi1, 256, 256);
  wconv<<<128, 256, 0, stream>>>(int_W2, wi2, 256, 128);
  wconv<<<256, 256, 0, stream>>>(msg_W1, wm1, 256, 256);
  wconv<<<128, 256, 0, stream>>>(msg_W2, wm2, 256, 128);
  wconv<<<160, 256, 0, stream>>>(upd_W1, wu1, 320, 128);
  wconv<<< 32, 256, 0, stream>>>(upd_W2, wu2, 128, 64);

  for (int ts = 0; ts < 2; ++ts) {
    // encoders (reset h, e)
    fused_mlp<32,64,64,0,1><<<NN/32, 256, 0, stream>>>(
        node_features, nullptr, enc_node_W, enc_node_b, nullptr, nullptr, h, -1);
    fused_mlp<32,128,128,0,1><<<NE/32, 256, 0, stream>>>(
        edge_features, nullptr, enc_edge_W, enc_edge_b, nullptr, nullptr, e, -1);

    for (int p = 0; p < 3; ++p) {
      // comb = intMLP([e, inter]) -> bf16   (inter==0 for ts0 and ts1/p0)
      const float* interArg = (ts == 1 && p > 0) ? inter : nullptr;
      mlp_mfma<256,256,128,4,0,1><<<NE/32, 256, 0, stream>>>(
          e, interArg, nullptr, nullptr, nullptr, nullptr,
          wi1, int_b1, wi2, int_b2, nullptr, comb, nullptr);
      // messages on old h -> mf, mb (bf16, in e's dead storage), both dirs
      mlp_mfma<256,256,128,1,1,2><<<NE/32, 256, 0, stream>>>(
          h, nullptr, nullptr, comb, from_idx, to_idx,
          wm1, msg_b1, wm2, msg_b2, nullptr, mfb, mbb);
      // pair-local segment sums (LDS), both dirs as blocks
      scatter_agg<<<BATCH*2, 256, 0, stream>>>(mfb, mbb, from_idx, to_idx, aggF, aggB);
      // node update (in place)
      mlp_mfma<320,128,64,3,0,0><<<NN/32, 256, 0, stream>>>(
          h, aggF, aggB, nullptr, nullptr, nullptr,
          wu1, upd_b1, wu2, upd_b2, h, nullptr, nullptr);
      // e = mf2 + mb2 with updated h (dual-direction sum; overwrites mf/mb)
      mlp_mfma<256,256,128,1,1,0><<<NE/32, 256, 0, stream>>>(
          h, nullptr, nullptr, comb, from_idx, to_idx,
          wm1, msg_b1, wm2, msg_b2, e, nullptr, nullptr);
      // interaction features from last time step's transport plan
      if (ts == 1 && p < 2) {
        gemm_plan<0><<<dim3(4, BATCH), 256, 0, stream>>>(
            S, e, inter, EPG, 0,   EQ_, EC_, EQ_);
        gemm_plan<1><<<dim3(4, BATCH), 256, 0, stream>>>(
            S, e, inter, EPG, EQ_, 0,   EQ_, EC_);
      }
    }
    // sinkhorn features + plan
    fused_mlp<128,64,64,5,0><<<BATCH*8, 256, 0, stream>>>(
        nullptr, e, sink_W1, sink_b1, sink_W2, sink_b2, fq, EQ_);
    fused_mlp<128,64,64,6,0><<<BATCH*8, 256, 0, stream>>>(
        nullptr, e, sink_W1, sink_b1, sink_W2, sink_b2, fc, EC_);
    gemm_nt_scale<<<dim3(4,4,BATCH), 256, 0, stream>>>(fq, fc, S, 10.0f);
    sinkhorn_fused<<<BATCH, 1024, 0, stream>>>(S);   // S := plan (register-resident)
  }

  // final score
  gemm_plan<0><<<dim3(4, BATCH), 256, 0, stream>>>(S, e, shr, 256, 0, EQ_, EC_, 256);
  escore_kernel<<<BATCH, 256, 0, stream>>>(e, shr, out);
}

// Round 10
// 4665.926 us; speedup vs baseline: 1.0686x; 1.0686x over previous
//
#include <hip/hip_runtime.h>
#include <math.h>

constexpr int BATCH = 256;
constexpr int EQ_   = 192;
constexpr int EC_   = 240;
constexpr int EPG   = 432;   // edges per pair
constexpr int NPG   = 216;   // nodes per pair
constexpr int NN    = BATCH * NPG;   // 55296
constexpr int NE    = BATCH * EPG;   // 110592

typedef __attribute__((ext_vector_type(8))) short short8;
typedef __attribute__((ext_vector_type(4))) float floatx4;
typedef unsigned short u16;

__device__ __forceinline__ u16 f2bf(float x) {
  union { float f; unsigned u; } c; c.f = x;
  const unsigned r = (c.u + 0x7FFFu + ((c.u >> 16) & 1u)) >> 16;
  return (u16)r;
}
__device__ __forceinline__ float bf2f(u16 x) {
  union { unsigned u; float f; } c; c.u = ((unsigned)x) << 16;
  return c.f;
}
__device__ __forceinline__ short8 cvt8(const float* __restrict__ p) {
  const float4 a = *(const float4*)p;
  const float4 b = *(const float4*)(p + 4);
  short8 o;
  o[0]=(short)f2bf(a.x); o[1]=(short)f2bf(a.y); o[2]=(short)f2bf(a.z); o[3]=(short)f2bf(a.w);
  o[4]=(short)f2bf(b.x); o[5]=(short)f2bf(b.y); o[6]=(short)f2bf(b.z); o[7]=(short)f2bf(b.w);
  return o;
}

__device__ __forceinline__ void lse_merge(float& m, float& s, float om, float os) {
  const float nm = fmaxf(m, om);
  s = s * __expf(m - nm) + os * __expf(om - nm);
  m = nm;
}
__device__ __forceinline__ void lse_online(float& m, float& s, float tt) {
  if (tt > m) { s = s * __expf(m - tt) + 1.f; m = tt; }
  else        { s += __expf(tt - m); }
}

// ---------------------------------------------------------------------------
// weight transpose + f32->bf16:  out[n*K+k] = bf16(W[k*N+n])
// ---------------------------------------------------------------------------
__global__ __launch_bounds__(256)
void wconv(const float* __restrict__ W, u16* __restrict__ out, int K, int N)
{
  const int i = blockIdx.x * 256 + threadIdx.x;
  if (i < K * N) {
    const int n = i / K, k = i - n * K;
    out[i] = f2bf(W[(size_t)k * N + n]);
  }
}

// ---------------------------------------------------------------------------
// MFMA fused 2-layer MLP, 32-row tiles, LDS union (sA aliases sH).
// (round-6 proven version)
// IN_MODE: 1 [h[IA],h[IB],comb]  3 [h,aggF,aggB]  4 [e, inter(or 0)]
// DUAL: also compute with first two 64-blocks swapped (k^64).
// OUT_MODE: 0 f32 write (sum over dirs)  1 bf16 write (sum)  2 bf16 per-dir -> Yb0/Yb1
// ---------------------------------------------------------------------------
template<int K1, int HID, int NOUT, int IN_MODE, int DUAL, int OUT_MODE>
__global__ __launch_bounds__(256, 4)
void mlp_mfma(const float* __restrict__ X, const float* __restrict__ P2,
              const float* __restrict__ P3, const u16* __restrict__ CB,
              const int* __restrict__ IA, const int* __restrict__ IB,
              const u16* __restrict__ W1t, const float* __restrict__ B1,
              const u16* __restrict__ W2t, const float* __restrict__ B2,
              float* __restrict__ Yf, u16* __restrict__ Yb0, u16* __restrict__ Yb1)
{
  constexpr int RT  = 32;
  constexpr int KCH = K1 / 8;
  constexpr int NT1 = HID / 64;
  constexpr int NT2 = (NOUT >= 64) ? NOUT / 64 : 1;
  constexpr int SAB = RT * K1 * 2;
  constexpr int SHB = RT * (HID + 8) * 2;
  __shared__ __align__(16) char smem[(SAB > SHB ? SAB : SHB)];
  u16* sA = (u16*)smem;
  u16* sH = (u16*)smem;

  const int tid = threadIdx.x;
  const int rowBase = blockIdx.x * RT;

  // ---- stage A panel (gather + cvt), XOR-swizzled rows ----
  for (int ch = tid; ch < RT * KCH; ch += 256) {
    const int r = ch / KCH, kc = ch - r * KCH;
    const int gr = rowBase + r, k0 = kc * 8;
    short8 pk;
    if constexpr (IN_MODE == 4) {
      if (k0 < 128)      pk = cvt8(&X[(size_t)gr * 128 + k0]);
      else if (P2)       pk = cvt8(&P2[(size_t)gr * 128 + (k0 - 128)]);
      else { pk = short8{0,0,0,0,0,0,0,0}; }
    } else if constexpr (IN_MODE == 1) {
      if (k0 < 64)       pk = cvt8(&X[(size_t)IA[gr] * 64 + k0]);
      else if (k0 < 128) pk = cvt8(&X[(size_t)IB[gr] * 64 + (k0 - 64)]);
      else               pk = *(const short8*)&CB[(size_t)gr * 128 + (k0 - 128)];
    } else { // 3
      if (k0 < 64)       pk = cvt8(&X[(size_t)gr * 64 + k0]);
      else if (k0 < 192) pk = cvt8(&P2[(size_t)gr * 128 + (k0 - 64)]);
      else               pk = cvt8(&P3[(size_t)gr * 128 + (k0 - 192)]);
    }
    const int byte = ((r * K1 + k0) * 2) ^ ((r & 7) << 4);
    *(short8*)((char*)sA + byte) = pk;
  }
  __syncthreads();

  const int wid = tid >> 6, lane = tid & 63;
  const int l15 = lane & 15, lg = lane >> 4;

  // ---- layer 1, all dirs (sA stays live only here) ----
  floatx4 acc1[1 + DUAL][2][NT1];
  #pragma unroll
  for (int d = 0; d <= DUAL; ++d)
    #pragma unroll
    for (int m = 0; m < 2; ++m)
      #pragma unroll
      for (int n = 0; n < NT1; ++n) acc1[d][m][n] = floatx4{0.f,0.f,0.f,0.f};

  #pragma unroll 2
  for (int kk = 0; kk < K1 / 32; ++kk) {
    short8 bw[NT1];
    #pragma unroll
    for (int n = 0; n < NT1; ++n) {
      const int col = wid * (HID / 4) + n * 16 + l15;
      bw[n] = *(const short8*)&W1t[(size_t)col * K1 + kk * 32 + lg * 8];
    }
    #pragma unroll
    for (int d = 0; d <= DUAL; ++d) {
      int k0 = kk * 32 + lg * 8;
      if (DUAL && d && k0 < 128) k0 ^= 64;
      #pragma unroll
      for (int m = 0; m < 2; ++m) {
        const int r = m * 16 + l15;
        const int byte = ((r * K1 + k0) * 2) ^ ((r & 7) << 4);
        const short8 af = *(const short8*)((char*)sA + byte);
        #pragma unroll
        for (int n = 0; n < NT1; ++n)
          acc1[d][m][n] = __builtin_amdgcn_mfma_f32_16x16x32_bf16(af, bw[n], acc1[d][m][n], 0, 0, 0);
      }
    }
  }
  __syncthreads();   // sA dead from here; smem becomes sH

  floatx4 accO[2][NT2];
  #pragma unroll
  for (int m = 0; m < 2; ++m)
    #pragma unroll
    for (int n = 0; n < NT2; ++n) accO[m][n] = floatx4{0.f,0.f,0.f,0.f};

  #pragma unroll
  for (int d = 0; d <= DUAL; ++d) {
    // hidden: bias + relu -> bf16 LDS
    #pragma unroll
    for (int n = 0; n < NT1; ++n) {
      const int col = wid * (HID / 4) + n * 16 + l15;
      const float b1 = B1[col];
      #pragma unroll
      for (int m = 0; m < 2; ++m)
        #pragma unroll
        for (int r = 0; r < 4; ++r) {
          const int row = m * 16 + lg * 4 + r;
          const float y = acc1[d][m][n][r] + b1;
          sH[row * (HID + 8) + col] = f2bf(y > 0.f ? y : 0.f);
        }
    }
    __syncthreads();
    if (OUT_MODE == 2 && d == 1) {
      #pragma unroll
      for (int m = 0; m < 2; ++m)
        #pragma unroll
        for (int n = 0; n < NT2; ++n) accO[m][n] = floatx4{0.f,0.f,0.f,0.f};
    }
    #pragma unroll 2
    for (int kk = 0; kk < HID / 32; ++kk) {
      short8 bw2[NT2];
      #pragma unroll
      for (int n = 0; n < NT2; ++n) {
        const int col = wid * (NOUT / 4) + n * 16 + l15;
        bw2[n] = *(const short8*)&W2t[(size_t)col * HID + kk * 32 + lg * 8];
      }
      #pragma unroll
      for (int m = 0; m < 2; ++m) {
        const short8 af = *(const short8*)&sH[(m * 16 + l15) * (HID + 8) + kk * 32 + lg * 8];
        #pragma unroll
        for (int n = 0; n < NT2; ++n)
          accO[m][n] = __builtin_amdgcn_mfma_f32_16x16x32_bf16(af, bw2[n], accO[m][n], 0, 0, 0);
      }
    }
    if constexpr (OUT_MODE == 2) {
      u16* Y = d ? Yb1 : Yb0;
      #pragma unroll
      for (int n = 0; n < NT2; ++n) {
        const int col = wid * (NOUT / 4) + n * 16 + l15;
        const float b2 = B2[col];
        #pragma unroll
        for (int m = 0; m < 2; ++m)
          #pragma unroll
          for (int r = 0; r < 4; ++r) {
            const int gr = rowBase + m * 16 + lg * 4 + r;
            Y[(size_t)gr * NOUT + col] = f2bf(accO[m][n][r] + b2);
          }
      }
    }
    if (DUAL && d == 0) __syncthreads();   // before overwriting sH
  }

  if constexpr (OUT_MODE != 2) {
    #pragma unroll
    for (int n = 0; n < NT2; ++n) {
      const int col = wid * (NOUT / 4) + n * 16 + l15;
      const float b2 = B2[col] * (float)(1 + DUAL);
      #pragma unroll
      for (int m = 0; m < 2; ++m)
        #pragma unroll
        for (int r = 0; r < 4; ++r) {
          const int gr = rowBase + m * 16 + lg * 4 + r;
          const float y = accO[m][n][r] + b2;
          if constexpr (OUT_MODE == 1) Yb0[(size_t)gr * NOUT + col] = f2bf(y);
          else                         Yf[(size_t)gr * NOUT + col] = y;
        }
    }
  }
}

// ---------------------------------------------------------------------------
// Pair-local segment-sum scatter: block = pair*2 + dir.
// ---------------------------------------------------------------------------
__global__ __launch_bounds__(256)
void scatter_agg(const u16* __restrict__ MF, const u16* __restrict__ MB,
                 const int* __restrict__ FI, const int* __restrict__ TI,
                 float* __restrict__ AggF, float* __restrict__ AggB)
{
  const int pair = blockIdx.x >> 1, dir = blockIdx.x & 1;
  const u16* M  = dir ? MB : MF;
  const int* SI = dir ? FI : TI;
  float* Agg    = dir ? AggB : AggF;
  const int tid = threadIdx.x;
  __shared__ float sAgg[NPG * 128];

  for (int i = tid; i < NPG * 128; i += 256) sAgg[i] = 0.f;
  __syncthreads();

  for (int i = tid; i < EPG * 32; i += 256) {
    const int edge = i >> 5, cb = i & 31;
    const int er = pair * EPG + edge;
    const int node = SI[er] - pair * NPG;
    const size_t base = (size_t)er * 128 + cb;
    #pragma unroll
    for (int k = 0; k < 4; ++k)
      atomicAdd(&sAgg[node * 128 + cb + 32 * k], bf2f(M[base + 32 * k]));
  }
  __syncthreads();
  float* dst = Agg + (size_t)pair * NPG * 128;
  for (int i = tid; i < NPG * 128; i += 256) dst[i] = sAgg[i];
}

// ---------------------------------------------------------------------------
// f32 fused MLP (encoders + sinkhorn feature MLPs)
// IN_MODE: 0 plain X  5 q-side rows of e (zero-padded)  6 c-side rows
// ---------------------------------------------------------------------------
template<int K1, int HID, int NOUT, int IN_MODE, int SINGLE>
__global__ __launch_bounds__(256)
void fused_mlp(const float* __restrict__ X, const float* __restrict__ P1,
               const float* __restrict__ W1, const float* __restrict__ B1,
               const float* __restrict__ W2, const float* __restrict__ B2,
               float* __restrict__ Y, int maskLen)
{
  constexpr int RT = 32, BK = 32;
  constexpr int J1 = HID / 32;
  constexpr int J2 = NOUT / 32;
  constexpr int BMAX = (HID > NOUT ? HID : NOUT);
  __shared__ float sA[RT * 33];
  __shared__ float sB[BK * BMAX];
  __shared__ float sH[SINGLE ? 1 : RT * (HID + 1)];

  const int t  = threadIdx.x;
  const int tx = t & 31, ty = t >> 5;
  const int rowBase = blockIdx.x * RT;

  float acc[4][J1];
  #pragma unroll
  for (int i = 0; i < 4; ++i)
    #pragma unroll
    for (int j = 0; j < J1; ++j) acc[i][j] = 0.f;

  for (int kb = 0; kb < K1; kb += BK) {
    for (int l = t; l < RT * BK; l += 256) {
      const int r = l >> 5, k = l & 31;
      const int gr = rowBase + r, gk = kb + k;
      float v;
      if constexpr (IN_MODE == 0) {
        v = X[(size_t)gr * K1 + gk];
      } else {
        const int bb = gr >> 8, m = gr & 255;
        constexpr int off = (IN_MODE == 5) ? 0 : EQ_;
        constexpr int len = (IN_MODE == 5) ? EQ_ : EC_;
        v = (m < len) ? P1[((size_t)bb * EPG + off + m) * 128 + gk] : 0.f;
      }
      sA[r * 33 + k] = v;
    }
    for (int l = t * 4; l < BK * HID; l += 1024) {
      *(float4*)&sB[l] = *(const float4*)&W1[(size_t)(kb + l / HID) * HID + (l % HID)];
    }
    __syncthreads();
    #pragma unroll
    for (int k = 0; k < BK; ++k) {
      const float a0 = sA[(ty*4+0)*33+k], a1 = sA[(ty*4+1)*33+k],
                  a2 = sA[(ty*4+2)*33+k], a3 = sA[(ty*4+3)*33+k];
      #pragma unroll
      for (int j = 0; j < J1; ++j) {
        const float bb = sB[k * HID + tx + 32*j];
        acc[0][j] += a0 * bb; acc[1][j] += a1 * bb;
        acc[2][j] += a2 * bb; acc[3][j] += a3 * bb;
      }
    }
    __syncthreads();
  }

  if constexpr (SINGLE) {
    #pragma unroll
    for (int j = 0; j < J1; ++j) {
      const int col = tx + 32*j;
      const float bias = B1[col];
      #pragma unroll
      for (int i = 0; i < 4; ++i) {
        const int gr = rowBase + ty*4 + i;
        Y[(size_t)gr * HID + col] = acc[i][j] + bias;
      }
    }
  } else {
    #pragma unroll
    for (int j = 0; j < J1; ++j) {
      const int col = tx + 32*j;
      const float bias = B1[col];
      #pragma unroll
      for (int i = 0; i < 4; ++i) {
        float y = acc[i][j] + bias;
        sH[(ty*4+i) * (HID+1) + col] = y > 0.f ? y : 0.f;
      }
    }
    __syncthreads();

    float acc2[4][J2];
    #pragma unroll
    for (int i = 0; i < 4; ++i)
      #pragma unroll
      for (int j = 0; j < J2; ++j) acc2[i][j] = 0.f;

    for (int kb = 0; kb < HID; kb += BK) {
      for (int l = t * 4; l < BK * NOUT; l += 1024) {
        *(float4*)&sB[l] = *(const float4*)&W2[(size_t)(kb + l / NOUT) * NOUT + (l % NOUT)];
      }
      __syncthreads();
      #pragma unroll
      for (int k = 0; k < BK; ++k) {
        const float a0 = sH[(ty*4+0)*(HID+1) + kb + k],
                    a1 = sH[(ty*4+1)*(HID+1) + kb + k],
                    a2 = sH[(ty*4+2)*(HID+1) + kb + k],
                    a3 = sH[(ty*4+3)*(HID+1) + kb + k];
        #pragma unroll
        for (int j = 0; j < J2; ++j) {
          const float bb = sB[k * NOUT + tx + 32*j];
          acc2[0][j] += a0 * bb; acc2[1][j] += a1 * bb;
          acc2[2][j] += a2 * bb; acc2[3][j] += a3 * bb;
        }
      }
      __syncthreads();
    }
    #pragma unroll
    for (int j = 0; j < J2; ++j) {
      const int col = tx + 32*j;
      const float bias = B2[col];
      #pragma unroll
      for (int i = 0; i < 4; ++i) {
        const int gr = rowBase + ty*4 + i;
        float y = acc2[i][j] + bias;
        if (maskLen >= 0 && (gr & 255) >= maskLen) y = 0.f;
        Y[(size_t)gr * NOUT + col] = y;
      }
    }
  }
}

// ---------------------------------------------------------------------------
// S[b] = scale * fq[b] @ fc[b]^T
// ---------------------------------------------------------------------------
__global__ __launch_bounds__(256)
void gemm_nt_scale(const float* __restrict__ A, const float* __restrict__ Bm,
                   float* __restrict__ C, float scale)
{
  const int b = blockIdx.z, qt = blockIdx.x, ct = blockIdx.y;
  __shared__ float sA[64 * 68];
  __shared__ float sB[64 * 68];
  const int t = threadIdx.x;
  const int tx = t & 15, ty = t >> 4;
  const float* Ab = A  + (size_t)b * 16384 + (size_t)qt * 4096;
  const float* Bb = Bm + (size_t)b * 16384 + (size_t)ct * 4096;
  for (int l = t * 4; l < 64 * 64; l += 1024) {
    const int r = l >> 6, d = l & 63;
    *(float4*)&sA[r*68 + d] = *(const float4*)&Ab[r*64 + d];
    *(float4*)&sB[r*68 + d] = *(const float4*)&Bb[r*64 + d];
  }
  __syncthreads();
  float acc[4][4] = {};
  #pragma unroll
  for (int d = 0; d < 64; ++d) {
    float a[4], bb[4];
    #pragma unroll
    for (int i = 0; i < 4; ++i) a[i]  = sA[(ty*4+i)*68 + d];
    #pragma unroll
    for (int j = 0; j < 4; ++j) bb[j] = sB[(tx+16*j)*68 + d];
    #pragma unroll
    for (int i = 0; i < 4; ++i)
      #pragma unroll
      for (int j = 0; j < 4; ++j) acc[i][j] += a[i] * bb[j];
  }
  float* Cb = C + (size_t)b * 65536 + (size_t)(qt*64) * 256 + ct*64;
  #pragma unroll
  for (int i = 0; i < 4; ++i)
    #pragma unroll
    for (int j = 0; j < 4; ++j)
      Cb[(ty*4+i)*256 + tx + 16*j] = acc[i][j] * scale;
}

// ---------------------------------------------------------------------------
// Y rows r<maskRows at ((b*RPB + YOFF + r)*128) = op(P[b]) @ V (gathered from e)
// ---------------------------------------------------------------------------
template<int TRANSA>
__global__ __launch_bounds__(256)
void gemm_plan(const float* __restrict__ P, const float* __restrict__ E,
               float* __restrict__ Y, int RPB, int YOFF, int VOFF, int VLEN,
               int maskRows)
{
  const int b = blockIdx.y, rt = blockIdx.x;
  __shared__ float sA[64 * 33];
  __shared__ float sB[32 * 128];
  const int t = threadIdx.x;
  const int tx = t & 15, ty = t >> 4;
  const float* Pb = P + (size_t)b * 65536;
  float acc[4][8] = {};
  for (int kb = 0; kb < 256; kb += 32) {
    if constexpr (TRANSA == 0) {
      for (int l = t; l < 64 * 32; l += 256) {
        const int r = l >> 5, k = l & 31;
        sA[r*33 + k] = Pb[(size_t)(rt*64 + r) * 256 + kb + k];
      }
    } else {
      for (int l = t; l < 64 * 32; l += 256) {
        const int r = l & 63, k = l >> 6;
        sA[r*33 + k] = Pb[(size_t)(kb + k) * 256 + rt*64 + r];
      }
    }
    for (int l = t * 4; l < 32 * 128; l += 1024) {
      const int vr = kb + (l >> 7), d = l & 127;
      float4 val = {0.f, 0.f, 0.f, 0.f};
      if (vr < VLEN) val = *(const float4*)&E[((size_t)b * EPG + VOFF + vr) * 128 + d];
      *(float4*)&sB[l] = val;
    }
    __syncthreads();
    #pragma unroll
    for (int k = 0; k < 32; ++k) {
      float a[4], bb[8];
      #pragma unroll
      for (int i = 0; i < 4; ++i) a[i]  = sA[(ty*4+i)*33 + k];
      #pragma unroll
      for (int j = 0; j < 8; ++j) bb[j] = sB[k*128 + tx + 16*j];
      #pragma unroll
      for (int i = 0; i < 4; ++i)
        #pragma unroll
        for (int j = 0; j < 8; ++j) acc[i][j] += a[i] * bb[j];
    }
    __syncthreads();
  }
  #pragma unroll
  for (int i = 0; i < 4; ++i) {
    const int r = rt*64 + ty*4 + i;
    if (r >= maskRows) continue;
    float* yr = Y + ((size_t)b * RPB + YOFF + r) * 128;
    #pragma unroll
    for (int j = 0; j < 8; ++j) yr[tx + 16*j] = acc[i][j];
  }
}

// ---------------------------------------------------------------------------
// Single-pass fused sinkhorn: block = pair, 1024 threads, ~25 VGPR state.
// Key identity: v_k[c] = -LSE_q(S[q,c]+u_k[q]) where u_k[r] is produced
// row-by-row. So ONE streamed pass per iteration: wave w reads its 16 rows,
// computes u[r] in flight (butterfly), and immediately folds exp(S[r,c]+u[r])
// into per-lane column partials. Cross-wave LDS merge yields v. S is read
// 10x (not 20x) and NO large register array exists -> nothing to spill
// (rounds 7-9 showed the allocator pins 1024-thread kernels at 64 VGPR).
// ---------------------------------------------------------------------------
__global__ __launch_bounds__(1024)
void sinkhorn_fused(float* __restrict__ S)
{
  const int b = blockIdx.x, t = threadIdx.x;
  float* Sb = S + (size_t)b * 65536;
  const int w = t >> 6, lane = t & 63;
  const int cbase = lane * 4;
  __shared__ float pm[16 * 256], ps[16 * 256];
  __shared__ float su[256], sv[256];
  if (t < 256) sv[t] = 0.f;
  __syncthreads();

  for (int it = 0; it < 10; ++it) {
    const float4 v4 = *(const float4*)&sv[cbase];
    float4 cm = {-1e30f, -1e30f, -1e30f, -1e30f};
    float4 cs = {0.f, 0.f, 0.f, 0.f};
    #pragma unroll 2
    for (int i = 0; i < 16; ++i) {
      const int r = w * 16 + i;
      const float4 s4 = *(const float4*)&Sb[(size_t)r * 256 + cbase];
      // row-LSE: u[r] = -LSE_c(S[r,c] + v[c]) via 64-lane butterfly
      float m = -1e30f, s = 0.f;
      lse_online(m, s, s4.x + v4.x);
      lse_online(m, s, s4.y + v4.y);
      lse_online(m, s, s4.z + v4.z);
      lse_online(m, s, s4.w + v4.w);
      #pragma unroll
      for (int off = 32; off; off >>= 1) {
        const float om = __shfl_xor(m, off);
        const float os = __shfl_xor(s, off);
        lse_merge(m, s, om, os);
      }
      const float u = -(m + __logf(s));
      if (lane == 0) su[r] = u;           // consumed only by planify
      // fold this row into the wave's column partials
      lse_online(cm.x, cs.x, s4.x + u);
      lse_online(cm.y, cs.y, s4.y + u);
      lse_online(cm.z, cs.z, s4.z + u);
      lse_online(cm.w, cs.w, s4.w + u);
    }
    *(float4*)&pm[w * 256 + cbase] = cm;
    *(float4*)&ps[w * 256 + cbase] = cs;
    __syncthreads();
    if (t < 256) {
      float m = pm[t], s = ps[t];
      #pragma unroll
      for (int k = 1; k < 16; ++k)
        lse_merge(m, s, pm[k * 256 + t], ps[k * 256 + t]);
      sv[t] = -(m + __logf(s));
    }
    __syncthreads();
  }
  // planify: S := exp(S + u + v)
  for (int i = t; i < 16384; i += 1024) {
    const int row = i >> 6, c4 = (i & 63) * 4;
    float4 s4 = *(float4*)&Sb[(size_t)row * 256 + c4];
    const float uu = su[row];
    const float4 v4 = *(const float4*)&sv[c4];
    s4.x = __expf(s4.x + uu + v4.x);
    s4.y = __expf(s4.y + uu + v4.y);
    s4.z = __expf(s4.z + uu + v4.z);
    s4.w = __expf(s4.w + uu + v4.w);
    *(float4*)&Sb[(size_t)row * 256 + c4] = s4;
  }
}

// ---------------------------------------------------------------------------
// score[b] = -sum_{m<256,d} | (m<EQ ? e_q[m,d] : 0) - pc[m,d] |
// ---------------------------------------------------------------------------
__global__ __launch_bounds__(256)
void escore_kernel(const float* __restrict__ e, const float* __restrict__ pc,
                   float* __restrict__ out)
{
  const int b = blockIdx.x, t = threadIdx.x;
  float acc = 0.f;
  for (int i4 = t; i4 < 8192; i4 += 256) {
    const int flat = i4 * 4;
    const int m = flat >> 7, d = flat & 127;
    float4 p = *(const float4*)&pc[((size_t)b * 256 + m) * 128 + d];
    float4 q = {0.f, 0.f, 0.f, 0.f};
    if (m < EQ_) q = *(const float4*)&e[((size_t)b * EPG + m) * 128 + d];
    acc += fabsf(q.x - p.x) + fabsf(q.y - p.y) + fabsf(q.z - p.z) + fabsf(q.w - p.w);
  }
  __shared__ float red[256];
  red[t] = acc; __syncthreads();
  for (int s2 = 128; s2 > 0; s2 >>= 1) { if (t < s2) red[t] += red[t + s2]; __syncthreads(); }
  if (t == 0) out[b] = -red[0];
}

// ---------------------------------------------------------------------------
extern "C" void kernel_launch(void* const* d_in, const int* in_sizes, int n_in,
                              void* d_out, int out_size, void* d_ws, size_t ws_size,
                              hipStream_t stream)
{
  const float* node_features = (const float*)d_in[0];
  const float* edge_features = (const float*)d_in[1];
  const int*   from_idx      = (const int*)d_in[2];
  const int*   to_idx        = (const int*)d_in[3];
  const float* enc_node_W = (const float*)d_in[4];
  const float* enc_node_b = (const float*)d_in[5];
  const float* enc_edge_W = (const float*)d_in[6];
  const float* enc_edge_b = (const float*)d_in[7];
  const float* msg_W1 = (const float*)d_in[8];
  const float* msg_b1 = (const float*)d_in[9];
  const float* msg_W2 = (const float*)d_in[10];
  const float* msg_b2 = (const float*)d_in[11];
  const float* upd_W1 = (const float*)d_in[12];
  const float* upd_b1 = (const float*)d_in[13];
  const float* upd_W2 = (const float*)d_in[14];
  const float* upd_b2 = (const float*)d_in[15];
  const float* int_W1 = (const float*)d_in[16];
  const float* int_b1 = (const float*)d_in[17];
  const float* int_W2 = (const float*)d_in[18];
  const float* int_b2 = (const float*)d_in[19];
  const float* sink_W1 = (const float*)d_in[20];
  const float* sink_b1 = (const float*)d_in[21];
  const float* sink_W2 = (const float*)d_in[22];
  const float* sink_b2 = (const float*)d_in[23];
  float* out = (float*)d_out;

  // ~224 MB layout (round-3/5/6/8 proven). mf/mb bf16 alias e's dead window.
  float* wsf = (float*)d_ws;
  float* h   = wsf;                               // NN*64 f32
  float* e   = h + (size_t)NN * 64;               // NE*128 f32
  float* shr = e + (size_t)NE * 128;              // NE*128 f32 (inter | aggF+aggB | fq+fc | pc)
  float* S   = shr + (size_t)NE * 128;            // BATCH*65536 f32
  u16* comb  = (u16*)(S + (size_t)BATCH * 65536); // NE*128 bf16
  u16* wi1 = comb + (size_t)NE * 128;             // 256x256
  u16* wi2 = wi1 + 65536;                         // 128x256
  u16* wm1 = wi2 + 32768;                         // 256x256
  u16* wm2 = wm1 + 65536;                         // 128x256
  u16* wu1 = wm2 + 32768;                         // 128x320
  u16* wu2 = wu1 + 40960;                         // 64x128

  u16* mfb = (u16*)e;                             // aliases e (dead window)
  u16* mbb = mfb + (size_t)NE * 128;

  float* aggF  = shr;
  float* aggB  = shr + (size_t)NN * 128;
  float* inter = shr;                             // EPG-row layout
  float* fq    = shr;
  float* fc    = shr + (size_t)BATCH * 16384;

  // weights -> bf16, transposed [N][K]
  wconv<<<256, 256, 0, stream>>>(int_W1, wi1, 256, 256);
  wconv<<<128, 256, 0, stream>>>(int_W2, wi2, 256, 128);
  wconv<<<256, 256, 0, stream>>>(msg_W1, wm1, 256, 256);
  wconv<<<128, 256, 0, stream>>>(msg_W2, wm2, 256, 128);
  wconv<<<160, 256, 0, stream>>>(upd_W1, wu1, 320, 128);
  wconv<<< 32, 256, 0, stream>>>(upd_W2, wu2, 128, 64);

  for (int ts = 0; ts < 2; ++ts) {
    // encoders (reset h, e)
    fused_mlp<32,64,64,0,1><<<NN/32, 256, 0, stream>>>(
        node_features, nullptr, enc_node_W, enc_node_b, nullptr, nullptr, h, -1);
    fused_mlp<32,128,128,0,1><<<NE/32, 256, 0, stream>>>(
        edge_features, nullptr, enc_edge_W, enc_edge_b, nullptr, nullptr, e, -1);

    for (int p = 0; p < 3; ++p) {
      // comb = intMLP([e, inter]) -> bf16   (inter==0 for ts0 and ts1/p0)
      const float* interArg = (ts == 1 && p > 0) ? inter : nullptr;
      mlp_mfma<256,256,128,4,0,1><<<NE/32, 256, 0, stream>>>(
          e, interArg, nullptr, nullptr, nullptr, nullptr,
          wi1, int_b1, wi2, int_b2, nullptr, comb, nullptr);
      // messages on old h -> mf, mb (bf16, in e's dead storage), both dirs
      mlp_mfma<256,256,128,1,1,2><<<NE/32, 256, 0, stream>>>(
          h, nullptr, nullptr, comb, from_idx, to_idx,
          wm1, msg_b1, wm2, msg_b2, nullptr, mfb, mbb);
      // pair-local segment sums (LDS), both dirs as blocks
      scatter_agg<<<BATCH*2, 256, 0, stream>>>(mfb, mbb, from_idx, to_idx, aggF, aggB);
      // node update (in place)
      mlp_mfma<320,128,64,3,0,0><<<NN/32, 256, 0, stream>>>(
          h, aggF, aggB, nullptr, nullptr, nullptr,
          wu1, upd_b1, wu2, upd_b2, h, nullptr, nullptr);
      // e = mf2 + mb2 with updated h (dual-direction sum; overwrites mf/mb)
      mlp_mfma<256,256,128,1,1,0><<<NE/32, 256, 0, stream>>>(
          h, nullptr, nullptr, comb, from_idx, to_idx,
          wm1, msg_b1, wm2, msg_b2, e, nullptr, nullptr);
      // interaction features from last time step's transport plan
      if (ts == 1 && p < 2) {
        gemm_plan<0><<<dim3(4, BATCH), 256, 0, stream>>>(
            S, e, inter, EPG, 0,   EQ_, EC_, EQ_);
        gemm_plan<1><<<dim3(4, BATCH), 256, 0, stream>>>(
            S, e, inter, EPG, EQ_, 0,   EQ_, EC_);
      }
    }
    // sinkhorn features + plan
    fused_mlp<128,64,64,5,0><<<BATCH*8, 256, 0, stream>>>(
        nullptr, e, sink_W1, sink_b1, sink_W2, sink_b2, fq, EQ_);
    fused_mlp<128,64,64,6,0><<<BATCH*8, 256, 0, stream>>>(
        nullptr, e, sink_W1, sink_b1, sink_W2, sink_b2, fc, EC_);
    gemm_nt_scale<<<dim3(4,4,BATCH), 256, 0, stream>>>(fq, fc, S, 10.0f);
    sinkhorn_fused<<<BATCH, 1024, 0, stream>>>(S);   // S := plan (single-pass/iter)
  }

  // final score
  gemm_plan<0><<<dim3(4, BATCH), 256, 0, stream>>>(S, e, shr, 256, 0, EQ_, EC_, 256);
  escore_kernel<<<BATCH, 256, 0, stream>>>(e, shr, out);
}

// Round 11
// 4561.155 us; speedup vs baseline: 1.0931x; 1.0230x over previous
//
#include <hip/hip_runtime.h>
#include <math.h>

constexpr int BATCH = 256;
constexpr int EQ_   = 192;
constexpr int EC_   = 240;
constexpr int EPG   = 432;   // edges per pair
constexpr int NPG   = 216;   // nodes per pair
constexpr int NN    = BATCH * NPG;   // 55296
constexpr int NE    = BATCH * EPG;   // 110592

typedef __attribute__((ext_vector_type(8))) short short8;
typedef __attribute__((ext_vector_type(4))) float floatx4;
typedef unsigned short u16;

__device__ __forceinline__ u16 f2bf(float x) {
  union { float f; unsigned u; } c; c.f = x;
  const unsigned r = (c.u + 0x7FFFu + ((c.u >> 16) & 1u)) >> 16;
  return (u16)r;
}
__device__ __forceinline__ float bf2f(u16 x) {
  union { unsigned u; float f; } c; c.u = ((unsigned)x) << 16;
  return c.f;
}
__device__ __forceinline__ short8 cvt8(const float* __restrict__ p) {
  const float4 a = *(const float4*)p;
  const float4 b = *(const float4*)(p + 4);
  short8 o;
  o[0]=(short)f2bf(a.x); o[1]=(short)f2bf(a.y); o[2]=(short)f2bf(a.z); o[3]=(short)f2bf(a.w);
  o[4]=(short)f2bf(b.x); o[5]=(short)f2bf(b.y); o[6]=(short)f2bf(b.z); o[7]=(short)f2bf(b.w);
  return o;
}

__device__ __forceinline__ void lse_merge(float& m, float& s, float om, float os) {
  const float nm = fmaxf(m, om);
  s = s * __expf(m - nm) + os * __expf(om - nm);
  m = nm;
}
__device__ __forceinline__ void lse_online(float& m, float& s, float tt) {
  if (tt > m) { s = s * __expf(m - tt) + 1.f; m = tt; }
  else        { s += __expf(tt - m); }
}

// ---------------------------------------------------------------------------
// weight transpose + f32->bf16:  out[n*K+k] = bf16(W[k*N+n])
// ---------------------------------------------------------------------------
__global__ __launch_bounds__(256)
void wconv(const float* __restrict__ W, u16* __restrict__ out, int K, int N)
{
  const int i = blockIdx.x * 256 + threadIdx.x;
  if (i < K * N) {
    const int n = i / K, k = i - n * K;
    out[i] = f2bf(W[(size_t)k * N + n]);
  }
}

// ---------------------------------------------------------------------------
// MFMA fused 2-layer MLP, 32-row tiles, LDS union (sA aliases sH).
// (round-6 proven version)
// IN_MODE: 1 [h[IA],h[IB],comb]  3 [h,aggF,aggB]  4 [e, inter(or 0)]
// DUAL: also compute with first two 64-blocks swapped (k^64).
// OUT_MODE: 0 f32 write (sum over dirs)  1 bf16 write (sum)  2 bf16 per-dir -> Yb0/Yb1
// ---------------------------------------------------------------------------
template<int K1, int HID, int NOUT, int IN_MODE, int DUAL, int OUT_MODE>
__global__ __launch_bounds__(256, 4)
void mlp_mfma(const float* __restrict__ X, const float* __restrict__ P2,
              const float* __restrict__ P3, const u16* __restrict__ CB,
              const int* __restrict__ IA, const int* __restrict__ IB,
              const u16* __restrict__ W1t, const float* __restrict__ B1,
              const u16* __restrict__ W2t, const float* __restrict__ B2,
              float* __restrict__ Yf, u16* __restrict__ Yb0, u16* __restrict__ Yb1)
{
  constexpr int RT  = 32;
  constexpr int KCH = K1 / 8;
  constexpr int NT1 = HID / 64;
  constexpr int NT2 = (NOUT >= 64) ? NOUT / 64 : 1;
  constexpr int SAB = RT * K1 * 2;
  constexpr int SHB = RT * (HID + 8) * 2;
  __shared__ __align__(16) char smem[(SAB > SHB ? SAB : SHB)];
  u16* sA = (u16*)smem;
  u16* sH = (u16*)smem;

  const int tid = threadIdx.x;
  const int rowBase = blockIdx.x * RT;

  // ---- stage A panel (gather + cvt), XOR-swizzled rows ----
  for (int ch = tid; ch < RT * KCH; ch += 256) {
    const int r = ch / KCH, kc = ch - r * KCH;
    const int gr = rowBase + r, k0 = kc * 8;
    short8 pk;
    if constexpr (IN_MODE == 4) {
      if (k0 < 128)      pk = cvt8(&X[(size_t)gr * 128 + k0]);
      else if (P2)       pk = cvt8(&P2[(size_t)gr * 128 + (k0 - 128)]);
      else { pk = short8{0,0,0,0,0,0,0,0}; }
    } else if constexpr (IN_MODE == 1) {
      if (k0 < 64)       pk = cvt8(&X[(size_t)IA[gr] * 64 + k0]);
      else if (k0 < 128) pk = cvt8(&X[(size_t)IB[gr] * 64 + (k0 - 64)]);
      else               pk = *(const short8*)&CB[(size_t)gr * 128 + (k0 - 128)];
    } else { // 3
      if (k0 < 64)       pk = cvt8(&X[(size_t)gr * 64 + k0]);
      else if (k0 < 192) pk = cvt8(&P2[(size_t)gr * 128 + (k0 - 64)]);
      else               pk = cvt8(&P3[(size_t)gr * 128 + (k0 - 192)]);
    }
    const int byte = ((r * K1 + k0) * 2) ^ ((r & 7) << 4);
    *(short8*)((char*)sA + byte) = pk;
  }
  __syncthreads();

  const int wid = tid >> 6, lane = tid & 63;
  const int l15 = lane & 15, lg = lane >> 4;

  // ---- layer 1, all dirs (sA stays live only here) ----
  floatx4 acc1[1 + DUAL][2][NT1];
  #pragma unroll
  for (int d = 0; d <= DUAL; ++d)
    #pragma unroll
    for (int m = 0; m < 2; ++m)
      #pragma unroll
      for (int n = 0; n < NT1; ++n) acc1[d][m][n] = floatx4{0.f,0.f,0.f,0.f};

  #pragma unroll 2
  for (int kk = 0; kk < K1 / 32; ++kk) {
    short8 bw[NT1];
    #pragma unroll
    for (int n = 0; n < NT1; ++n) {
      const int col = wid * (HID / 4) + n * 16 + l15;
      bw[n] = *(const short8*)&W1t[(size_t)col * K1 + kk * 32 + lg * 8];
    }
    #pragma unroll
    for (int d = 0; d <= DUAL; ++d) {
      int k0 = kk * 32 + lg * 8;
      if (DUAL && d && k0 < 128) k0 ^= 64;
      #pragma unroll
      for (int m = 0; m < 2; ++m) {
        const int r = m * 16 + l15;
        const int byte = ((r * K1 + k0) * 2) ^ ((r & 7) << 4);
        const short8 af = *(const short8*)((char*)sA + byte);
        #pragma unroll
        for (int n = 0; n < NT1; ++n)
          acc1[d][m][n] = __builtin_amdgcn_mfma_f32_16x16x32_bf16(af, bw[n], acc1[d][m][n], 0, 0, 0);
      }
    }
  }
  __syncthreads();   // sA dead from here; smem becomes sH

  floatx4 accO[2][NT2];
  #pragma unroll
  for (int m = 0; m < 2; ++m)
    #pragma unroll
    for (int n = 0; n < NT2; ++n) accO[m][n] = floatx4{0.f,0.f,0.f,0.f};

  #pragma unroll
  for (int d = 0; d <= DUAL; ++d) {
    // hidden: bias + relu -> bf16 LDS
    #pragma unroll
    for (int n = 0; n < NT1; ++n) {
      const int col = wid * (HID / 4) + n * 16 + l15;
      const float b1 = B1[col];
      #pragma unroll
      for (int m = 0; m < 2; ++m)
        #pragma unroll
        for (int r = 0; r < 4; ++r) {
          const int row = m * 16 + lg * 4 + r;
          const float y = acc1[d][m][n][r] + b1;
          sH[row * (HID + 8) + col] = f2bf(y > 0.f ? y : 0.f);
        }
    }
    __syncthreads();
    if (OUT_MODE == 2 && d == 1) {
      #pragma unroll
      for (int m = 0; m < 2; ++m)
        #pragma unroll
        for (int n = 0; n < NT2; ++n) accO[m][n] = floatx4{0.f,0.f,0.f,0.f};
    }
    #pragma unroll 2
    for (int kk = 0; kk < HID / 32; ++kk) {
      short8 bw2[NT2];
      #pragma unroll
      for (int n = 0; n < NT2; ++n) {
        const int col = wid * (NOUT / 4) + n * 16 + l15;
        bw2[n] = *(const short8*)&W2t[(size_t)col * HID + kk * 32 + lg * 8];
      }
      #pragma unroll
      for (int m = 0; m < 2; ++m) {
        const short8 af = *(const short8*)&sH[(m * 16 + l15) * (HID + 8) + kk * 32 + lg * 8];
        #pragma unroll
        for (int n = 0; n < NT2; ++n)
          accO[m][n] = __builtin_amdgcn_mfma_f32_16x16x32_bf16(af, bw2[n], accO[m][n], 0, 0, 0);
      }
    }
    if constexpr (OUT_MODE == 2) {
      u16* Y = d ? Yb1 : Yb0;
      #pragma unroll
      for (int n = 0; n < NT2; ++n) {
        const int col = wid * (NOUT / 4) + n * 16 + l15;
        const float b2 = B2[col];
        #pragma unroll
        for (int m = 0; m < 2; ++m)
          #pragma unroll
          for (int r = 0; r < 4; ++r) {
            const int gr = rowBase + m * 16 + lg * 4 + r;
            Y[(size_t)gr * NOUT + col] = f2bf(accO[m][n][r] + b2);
          }
      }
    }
    if (DUAL && d == 0) __syncthreads();   // before overwriting sH
  }

  if constexpr (OUT_MODE != 2) {
    #pragma unroll
    for (int n = 0; n < NT2; ++n) {
      const int col = wid * (NOUT / 4) + n * 16 + l15;
      const float b2 = B2[col] * (float)(1 + DUAL);
      #pragma unroll
      for (int m = 0; m < 2; ++m)
        #pragma unroll
        for (int r = 0; r < 4; ++r) {
          const int gr = rowBase + m * 16 + lg * 4 + r;
          const float y = accO[m][n][r] + b2;
          if constexpr (OUT_MODE == 1) Yb0[(size_t)gr * NOUT + col] = f2bf(y);
          else                         Yf[(size_t)gr * NOUT + col] = y;
        }
    }
  }
}

// ---------------------------------------------------------------------------
// Pair-local segment-sum scatter: block = pair*2 + dir.
// ---------------------------------------------------------------------------
__global__ __launch_bounds__(256)
void scatter_agg(const u16* __restrict__ MF, const u16* __restrict__ MB,
                 const int* __restrict__ FI, const int* __restrict__ TI,
                 float* __restrict__ AggF, float* __restrict__ AggB)
{
  const int pair = blockIdx.x >> 1, dir = blockIdx.x & 1;
  const u16* M  = dir ? MB : MF;
  const int* SI = dir ? FI : TI;
  float* Agg    = dir ? AggB : AggF;
  const int tid = threadIdx.x;
  __shared__ float sAgg[NPG * 128];

  for (int i = tid; i < NPG * 128; i += 256) sAgg[i] = 0.f;
  __syncthreads();

  for (int i = tid; i < EPG * 32; i += 256) {
    const int edge = i >> 5, cb = i & 31;
    const int er = pair * EPG + edge;
    const int node = SI[er] - pair * NPG;
    const size_t base = (size_t)er * 128 + cb;
    #pragma unroll
    for (int k = 0; k < 4; ++k)
      atomicAdd(&sAgg[node * 128 + cb + 32 * k], bf2f(M[base + 32 * k]));
  }
  __syncthreads();
  float* dst = Agg + (size_t)pair * NPG * 128;
  for (int i = tid; i < NPG * 128; i += 256) dst[i] = sAgg[i];
}

// ---------------------------------------------------------------------------
// f32 fused MLP (encoders + sinkhorn feature MLPs)
// IN_MODE: 0 plain X  5 q-side rows of e (zero-padded)  6 c-side rows
// ---------------------------------------------------------------------------
template<int K1, int HID, int NOUT, int IN_MODE, int SINGLE>
__global__ __launch_bounds__(256)
void fused_mlp(const float* __restrict__ X, const float* __restrict__ P1,
               const float* __restrict__ W1, const float* __restrict__ B1,
               const float* __restrict__ W2, const float* __restrict__ B2,
               float* __restrict__ Y, int maskLen)
{
  constexpr int RT = 32, BK = 32;
  constexpr int J1 = HID / 32;
  constexpr int J2 = NOUT / 32;
  constexpr int BMAX = (HID > NOUT ? HID : NOUT);
  __shared__ float sA[RT * 33];
  __shared__ float sB[BK * BMAX];
  __shared__ float sH[SINGLE ? 1 : RT * (HID + 1)];

  const int t  = threadIdx.x;
  const int tx = t & 31, ty = t >> 5;
  const int rowBase = blockIdx.x * RT;

  float acc[4][J1];
  #pragma unroll
  for (int i = 0; i < 4; ++i)
    #pragma unroll
    for (int j = 0; j < J1; ++j) acc[i][j] = 0.f;

  for (int kb = 0; kb < K1; kb += BK) {
    for (int l = t; l < RT * BK; l += 256) {
      const int r = l >> 5, k = l & 31;
      const int gr = rowBase + r, gk = kb + k;
      float v;
      if constexpr (IN_MODE == 0) {
        v = X[(size_t)gr * K1 + gk];
      } else {
        const int bb = gr >> 8, m = gr & 255;
        constexpr int off = (IN_MODE == 5) ? 0 : EQ_;
        constexpr int len = (IN_MODE == 5) ? EQ_ : EC_;
        v = (m < len) ? P1[((size_t)bb * EPG + off + m) * 128 + gk] : 0.f;
      }
      sA[r * 33 + k] = v;
    }
    for (int l = t * 4; l < BK * HID; l += 1024) {
      *(float4*)&sB[l] = *(const float4*)&W1[(size_t)(kb + l / HID) * HID + (l % HID)];
    }
    __syncthreads();
    #pragma unroll
    for (int k = 0; k < BK; ++k) {
      const float a0 = sA[(ty*4+0)*33+k], a1 = sA[(ty*4+1)*33+k],
                  a2 = sA[(ty*4+2)*33+k], a3 = sA[(ty*4+3)*33+k];
      #pragma unroll
      for (int j = 0; j < J1; ++j) {
        const float bb = sB[k * HID + tx + 32*j];
        acc[0][j] += a0 * bb; acc[1][j] += a1 * bb;
        acc[2][j] += a2 * bb; acc[3][j] += a3 * bb;
      }
    }
    __syncthreads();
  }

  if constexpr (SINGLE) {
    #pragma unroll
    for (int j = 0; j < J1; ++j) {
      const int col = tx + 32*j;
      const float bias = B1[col];
      #pragma unroll
      for (int i = 0; i < 4; ++i) {
        const int gr = rowBase + ty*4 + i;
        Y[(size_t)gr * HID + col] = acc[i][j] + bias;
      }
    }
  } else {
    #pragma unroll
    for (int j = 0; j < J1; ++j) {
      const int col = tx + 32*j;
      const float bias = B1[col];
      #pragma unroll
      for (int i = 0; i < 4; ++i) {
        float y = acc[i][j] + bias;
        sH[(ty*4+i) * (HID+1) + col] = y > 0.f ? y : 0.f;
      }
    }
    __syncthreads();

    float acc2[4][J2];
    #pragma unroll
    for (int i = 0; i < 4; ++i)
      #pragma unroll
      for (int j = 0; j < J2; ++j) acc2[i][j] = 0.f;

    for (int kb = 0; kb < HID; kb += BK) {
      for (int l = t * 4; l < BK * NOUT; l += 1024) {
        *(float4*)&sB[l] = *(const float4*)&W2[(size_t)(kb + l / NOUT) * NOUT + (l % NOUT)];
      }
      __syncthreads();
      #pragma unroll
      for (int k = 0; k < BK; ++k) {
        const float a0 = sH[(ty*4+0)*(HID+1) + kb + k],
                    a1 = sH[(ty*4+1)*(HID+1) + kb + k],
                    a2 = sH[(ty*4+2)*(HID+1) + kb + k],
                    a3 = sH[(ty*4+3)*(HID+1) + kb + k];
        #pragma unroll
        for (int j = 0; j < J2; ++j) {
          const float bb = sB[k * NOUT + tx + 32*j];
          acc2[0][j] += a0 * bb; acc2[1][j] += a1 * bb;
          acc2[2][j] += a2 * bb; acc2[3][j] += a3 * bb;
        }
      }
      __syncthreads();
    }
    #pragma unroll
    for (int j = 0; j < J2; ++j) {
      const int col = tx + 32*j;
      const float bias = B2[col];
      #pragma unroll
      for (int i = 0; i < 4; ++i) {
        const int gr = rowBase + ty*4 + i;
        float y = acc2[i][j] + bias;
        if (maskLen >= 0 && (gr & 255) >= maskLen) y = 0.f;
        Y[(size_t)gr * NOUT + col] = y;
      }
    }
  }
}

// ---------------------------------------------------------------------------
// S[b] = scale * fq[b] @ fc[b]^T
// ---------------------------------------------------------------------------
__global__ __launch_bounds__(256)
void gemm_nt_scale(const float* __restrict__ A, const float* __restrict__ Bm,
                   float* __restrict__ C, float scale)
{
  const int b = blockIdx.z, qt = blockIdx.x, ct = blockIdx.y;
  __shared__ float sA[64 * 68];
  __shared__ float sB[64 * 68];
  const int t = threadIdx.x;
  const int tx = t & 15, ty = t >> 4;
  const float* Ab = A  + (size_t)b * 16384 + (size_t)qt * 4096;
  const float* Bb = Bm + (size_t)b * 16384 + (size_t)ct * 4096;
  for (int l = t * 4; l < 64 * 64; l += 1024) {
    const int r = l >> 6, d = l & 63;
    *(float4*)&sA[r*68 + d] = *(const float4*)&Ab[r*64 + d];
    *(float4*)&sB[r*68 + d] = *(const float4*)&Bb[r*64 + d];
  }
  __syncthreads();
  float acc[4][4] = {};
  #pragma unroll
  for (int d = 0; d < 64; ++d) {
    float a[4], bb[4];
    #pragma unroll
    for (int i = 0; i < 4; ++i) a[i]  = sA[(ty*4+i)*68 + d];
    #pragma unroll
    for (int j = 0; j < 4; ++j) bb[j] = sB[(tx+16*j)*68 + d];
    #pragma unroll
    for (int i = 0; i < 4; ++i)
      #pragma unroll
      for (int j = 0; j < 4; ++j) acc[i][j] += a[i] * bb[j];
  }
  float* Cb = C + (size_t)b * 65536 + (size_t)(qt*64) * 256 + ct*64;
  #pragma unroll
  for (int i = 0; i < 4; ++i)
    #pragma unroll
    for (int j = 0; j < 4; ++j)
      Cb[(ty*4+i)*256 + tx + 16*j] = acc[i][j] * scale;
}

// ---------------------------------------------------------------------------
// Y rows r<maskRows at ((b*RPB + YOFF + r)*128) = op(P[b]) @ V (gathered from e)
// ---------------------------------------------------------------------------
template<int TRANSA>
__global__ __launch_bounds__(256)
void gemm_plan(const float* __restrict__ P, const float* __restrict__ E,
               float* __restrict__ Y, int RPB, int YOFF, int VOFF, int VLEN,
               int maskRows)
{
  const int b = blockIdx.y, rt = blockIdx.x;
  __shared__ float sA[64 * 33];
  __shared__ float sB[32 * 128];
  const int t = threadIdx.x;
  const int tx = t & 15, ty = t >> 4;
  const float* Pb = P + (size_t)b * 65536;
  float acc[4][8] = {};
  for (int kb = 0; kb < 256; kb += 32) {
    if constexpr (TRANSA == 0) {
      for (int l = t; l < 64 * 32; l += 256) {
        const int r = l >> 5, k = l & 31;
        sA[r*33 + k] = Pb[(size_t)(rt*64 + r) * 256 + kb + k];
      }
    } else {
      for (int l = t; l < 64 * 32; l += 256) {
        const int r = l & 63, k = l >> 6;
        sA[r*33 + k] = Pb[(size_t)(kb + k) * 256 + rt*64 + r];
      }
    }
    for (int l = t * 4; l < 32 * 128; l += 1024) {
      const int vr = kb + (l >> 7), d = l & 127;
      float4 val = {0.f, 0.f, 0.f, 0.f};
      if (vr < VLEN) val = *(const float4*)&E[((size_t)b * EPG + VOFF + vr) * 128 + d];
      *(float4*)&sB[l] = val;
    }
    __syncthreads();
    #pragma unroll
    for (int k = 0; k < 32; ++k) {
      float a[4], bb[8];
      #pragma unroll
      for (int i = 0; i < 4; ++i) a[i]  = sA[(ty*4+i)*33 + k];
      #pragma unroll
      for (int j = 0; j < 8; ++j) bb[j] = sB[k*128 + tx + 16*j];
      #pragma unroll
      for (int i = 0; i < 4; ++i)
        #pragma unroll
        for (int j = 0; j < 8; ++j) acc[i][j] += a[i] * bb[j];
    }
    __syncthreads();
  }
  #pragma unroll
  for (int i = 0; i < 4; ++i) {
    const int r = rt*64 + ty*4 + i;
    if (r >= maskRows) continue;
    float* yr = Y + ((size_t)b * RPB + YOFF + r) * 128;
    #pragma unroll
    for (int j = 0; j < 8; ++j) yr[tx + 16*j] = acc[i][j];
  }
}

// ---------------------------------------------------------------------------
// Single-pass fused sinkhorn with exp-free butterflies.
// Round-10 showed VALUBusy 86.7% -> VALU-bound; the online-LSE butterfly
// spent 12 exps/row in lse_merge. Split into max-butterfly (pure v_max) +
// shared-max exps (4) + add-butterfly (pure adds): 20 -> 9 transcendentals
// per row per lane. Col fold stays stable online (exact semantics).
// Cross-wave merge likewise max-loop + exp-mul-loop (30 -> 16 exps).
// ---------------------------------------------------------------------------
__global__ __launch_bounds__(1024)
void sinkhorn_fused(float* __restrict__ S)
{
  const int b = blockIdx.x, t = threadIdx.x;
  float* Sb = S + (size_t)b * 65536;
  const int w = t >> 6, lane = t & 63;
  const int cbase = lane * 4;
  __shared__ float pm[16 * 256], ps[16 * 256];
  __shared__ float su[256], sv[256];
  if (t < 256) sv[t] = 0.f;
  __syncthreads();

  for (int it = 0; it < 10; ++it) {
    const float4 v4 = *(const float4*)&sv[cbase];
    float4 cm = {-1e30f, -1e30f, -1e30f, -1e30f};
    float4 cs = {0.f, 0.f, 0.f, 0.f};
    #pragma unroll 2
    for (int i = 0; i < 16; ++i) {
      const int r = w * 16 + i;
      const float4 s4 = *(const float4*)&Sb[(size_t)r * 256 + cbase];
      const float ax = s4.x + v4.x, ay = s4.y + v4.y;
      const float az = s4.z + v4.z, aw = s4.w + v4.w;
      // row max: pure max butterfly (no exps)
      float m = fmaxf(fmaxf(ax, ay), fmaxf(az, aw));
      #pragma unroll
      for (int off = 32; off; off >>= 1) m = fmaxf(m, __shfl_xor(m, off));
      // row sum of exps against the global row max, add butterfly
      float s = __expf(ax - m) + __expf(ay - m) + __expf(az - m) + __expf(aw - m);
      #pragma unroll
      for (int off = 32; off; off >>= 1) s += __shfl_xor(s, off);
      const float u = -(m + __logf(s));
      if (lane == 0) su[r] = u;           // consumed only by planify
      // fold this row into the wave's column partials (stable online)
      lse_online(cm.x, cs.x, s4.x + u);
      lse_online(cm.y, cs.y, s4.y + u);
      lse_online(cm.z, cs.z, s4.z + u);
      lse_online(cm.w, cs.w, s4.w + u);
    }
    *(float4*)&pm[w * 256 + cbase] = cm;
    *(float4*)&ps[w * 256 + cbase] = cs;
    __syncthreads();
    if (t < 256) {
      float m = pm[t];
      #pragma unroll
      for (int k = 1; k < 16; ++k) m = fmaxf(m, pm[k * 256 + t]);
      float s = 0.f;
      #pragma unroll
      for (int k = 0; k < 16; ++k) s += ps[k * 256 + t] * __expf(pm[k * 256 + t] - m);
      sv[t] = -(m + __logf(s));
    }
    __syncthreads();
  }
  // planify: S := exp(S + u + v)
  for (int i = t; i < 16384; i += 1024) {
    const int row = i >> 6, c4 = (i & 63) * 4;
    float4 s4 = *(float4*)&Sb[(size_t)row * 256 + c4];
    const float uu = su[row];
    const float4 v4 = *(const float4*)&sv[c4];
    s4.x = __expf(s4.x + uu + v4.x);
    s4.y = __expf(s4.y + uu + v4.y);
    s4.z = __expf(s4.z + uu + v4.z);
    s4.w = __expf(s4.w + uu + v4.w);
    *(float4*)&Sb[(size_t)row * 256 + c4] = s4;
  }
}

// ---------------------------------------------------------------------------
// score[b] = -sum_{m<256,d} | (m<EQ ? e_q[m,d] : 0) - pc[m,d] |
// ---------------------------------------------------------------------------
__global__ __launch_bounds__(256)
void escore_kernel(const float* __restrict__ e, const float* __restrict__ pc,
                   float* __restrict__ out)
{
  const int b = blockIdx.x, t = threadIdx.x;
  float acc = 0.f;
  for (int i4 = t; i4 < 8192; i4 += 256) {
    const int flat = i4 * 4;
    const int m = flat >> 7, d = flat & 127;
    float4 p = *(const float4*)&pc[((size_t)b * 256 + m) * 128 + d];
    float4 q = {0.f, 0.f, 0.f, 0.f};
    if (m < EQ_) q = *(const float4*)&e[((size_t)b * EPG + m) * 128 + d];
    acc += fabsf(q.x - p.x) + fabsf(q.y - p.y) + fabsf(q.z - p.z) + fabsf(q.w - p.w);
  }
  __shared__ float red[256];
  red[t] = acc; __syncthreads();
  for (int s2 = 128; s2 > 0; s2 >>= 1) { if (t < s2) red[t] += red[t + s2]; __syncthreads(); }
  if (t == 0) out[b] = -red[0];
}

// ---------------------------------------------------------------------------
extern "C" void kernel_launch(void* const* d_in, const int* in_sizes, int n_in,
                              void* d_out, int out_size, void* d_ws, size_t ws_size,
                              hipStream_t stream)
{
  const float* node_features = (const float*)d_in[0];
  const float* edge_features = (const float*)d_in[1];
  const int*   from_idx      = (const int*)d_in[2];
  const int*   to_idx        = (const int*)d_in[3];
  const float* enc_node_W = (const float*)d_in[4];
  const float* enc_node_b = (const float*)d_in[5];
  const float* enc_edge_W = (const float*)d_in[6];
  const float* enc_edge_b = (const float*)d_in[7];
  const float* msg_W1 = (const float*)d_in[8];
  const float* msg_b1 = (const float*)d_in[9];
  const float* msg_W2 = (const float*)d_in[10];
  const float* msg_b2 = (const float*)d_in[11];
  const float* upd_W1 = (const float*)d_in[12];
  const float* upd_b1 = (const float*)d_in[13];
  const float* upd_W2 = (const float*)d_in[14];
  const float* upd_b2 = (const float*)d_in[15];
  const float* int_W1 = (const float*)d_in[16];
  const float* int_b1 = (const float*)d_in[17];
  const float* int_W2 = (const float*)d_in[18];
  const float* int_b2 = (const float*)d_in[19];
  const float* sink_W1 = (const float*)d_in[20];
  const float* sink_b1 = (const float*)d_in[21];
  const float* sink_W2 = (const float*)d_in[22];
  const float* sink_b2 = (const float*)d_in[23];
  float* out = (float*)d_out;

  // ~224 MB layout (round-3/5/6/8 proven). mf/mb bf16 alias e's dead window.
  float* wsf = (float*)d_ws;
  float* h   = wsf;                               // NN*64 f32
  float* e   = h + (size_t)NN * 64;               // NE*128 f32
  float* shr = e + (size_t)NE * 128;              // NE*128 f32 (inter | aggF+aggB | fq+fc | pc)
  float* S   = shr + (size_t)NE * 128;            // BATCH*65536 f32
  u16* comb  = (u16*)(S + (size_t)BATCH * 65536); // NE*128 bf16
  u16* wi1 = comb + (size_t)NE * 128;             // 256x256
  u16* wi2 = wi1 + 65536;                         // 128x256
  u16* wm1 = wi2 + 32768;                         // 256x256
  u16* wm2 = wm1 + 65536;                         // 128x256
  u16* wu1 = wm2 + 32768;                         // 128x320
  u16* wu2 = wu1 + 40960;                         // 64x128

  u16* mfb = (u16*)e;                             // aliases e (dead window)
  u16* mbb = mfb + (size_t)NE * 128;

  float* aggF  = shr;
  float* aggB  = shr + (size_t)NN * 128;
  float* inter = shr;                             // EPG-row layout
  float* fq    = shr;
  float* fc    = shr + (size_t)BATCH * 16384;

  // weights -> bf16, transposed [N][K]
  wconv<<<256, 256, 0, stream>>>(int_W1, wi1, 256, 256);
  wconv<<<128, 256, 0, stream>>>(int_W2, wi2, 256, 128);
  wconv<<<256, 256, 0, stream>>>(msg_W1, wm1, 256, 256);
  wconv<<<128, 256, 0, stream>>>(msg_W2, wm2, 256, 128);
  wconv<<<160, 256, 0, stream>>>(upd_W1, wu1, 320, 128);
  wconv<<< 32, 256, 0, stream>>>(upd_W2, wu2, 128, 64);

  for (int ts = 0; ts < 2; ++ts) {
    // encoders (reset h, e)
    fused_mlp<32,64,64,0,1><<<NN/32, 256, 0, stream>>>(
        node_features, nullptr, enc_node_W, enc_node_b, nullptr, nullptr, h, -1);
    fused_mlp<32,128,128,0,1><<<NE/32, 256, 0, stream>>>(
        edge_features, nullptr, enc_edge_W, enc_edge_b, nullptr, nullptr, e, -1);

    for (int p = 0; p < 3; ++p) {
      // comb = intMLP([e, inter]) -> bf16   (inter==0 for ts0 and ts1/p0)
      const float* interArg = (ts == 1 && p > 0) ? inter : nullptr;
      mlp_mfma<256,256,128,4,0,1><<<NE/32, 256, 0, stream>>>(
          e, interArg, nullptr, nullptr, nullptr, nullptr,
          wi1, int_b1, wi2, int_b2, nullptr, comb, nullptr);
      // messages on old h -> mf, mb (bf16, in e's dead storage), both dirs
      mlp_mfma<256,256,128,1,1,2><<<NE/32, 256, 0, stream>>>(
          h, nullptr, nullptr, comb, from_idx, to_idx,
          wm1, msg_b1, wm2, msg_b2, nullptr, mfb, mbb);
      // pair-local segment sums (LDS), both dirs as blocks
      scatter_agg<<<BATCH*2, 256, 0, stream>>>(mfb, mbb, from_idx, to_idx, aggF, aggB);
      // node update (in place)
      mlp_mfma<320,128,64,3,0,0><<<NN/32, 256, 0, stream>>>(
          h, aggF, aggB, nullptr, nullptr, nullptr,
          wu1, upd_b1, wu2, upd_b2, h, nullptr, nullptr);
      // e = mf2 + mb2 with updated h (dual-direction sum; overwrites mf/mb)
      mlp_mfma<256,256,128,1,1,0><<<NE/32, 256, 0, stream>>>(
          h, nullptr, nullptr, comb, from_idx, to_idx,
          wm1, msg_b1, wm2, msg_b2, e, nullptr, nullptr);
      // interaction features from last time step's transport plan
      if (ts == 1 && p < 2) {
        gemm_plan<0><<<dim3(4, BATCH), 256, 0, stream>>>(
            S, e, inter, EPG, 0,   EQ_, EC_, EQ_);
        gemm_plan<1><<<dim3(4, BATCH), 256, 0, stream>>>(
            S, e, inter, EPG, EQ_, 0,   EQ_, EC_);
      }
    }
    // sinkhorn features + plan
    fused_mlp<128,64,64,5,0><<<BATCH*8, 256, 0, stream>>>(
        nullptr, e, sink_W1, sink_b1, sink_W2, sink_b2, fq, EQ_);
    fused_mlp<128,64,64,6,0><<<BATCH*8, 256, 0, stream>>>(
        nullptr, e, sink_W1, sink_b1, sink_W2, sink_b2, fc, EC_);
    gemm_nt_scale<<<dim3(4,4,BATCH), 256, 0, stream>>>(fq, fc, S, 10.0f);
    sinkhorn_fused<<<BATCH, 1024, 0, stream>>>(S);   // S := plan
  }

  // final score
  gemm_plan<0><<<dim3(4, BATCH), 256, 0, stream>>>(S, e, shr, 256, 0, EQ_, EC_, 256);
  escore_kernel<<<BATCH, 256, 0, stream>>>(e, shr, out);
}

// Round 12
// 4299.294 us; speedup vs baseline: 1.1597x; 1.0609x over previous
//
#include <hip/hip_runtime.h>
#include <math.h>

constexpr int BATCH = 256;
constexpr int EQ_   = 192;
constexpr int EC_   = 240;
constexpr int EPG   = 432;   // edges per pair
constexpr int NPG   = 216;   // nodes per pair
constexpr int NN    = BATCH * NPG;   // 55296
constexpr int NE    = BATCH * EPG;   // 110592

typedef __attribute__((ext_vector_type(8))) short short8;
typedef __attribute__((ext_vector_type(4))) float floatx4;
typedef unsigned short u16;

__device__ __forceinline__ u16 f2bf(float x) {
  union { float f; unsigned u; } c; c.f = x;
  const unsigned r = (c.u + 0x7FFFu + ((c.u >> 16) & 1u)) >> 16;
  return (u16)r;
}
__device__ __forceinline__ float bf2f(u16 x) {
  union { unsigned u; float f; } c; c.u = ((unsigned)x) << 16;
  return c.f;
}
__device__ __forceinline__ unsigned pack2(float a, float b) {
  return (unsigned)f2bf(a) | ((unsigned)f2bf(b) << 16);
}
__device__ __forceinline__ short8 cvt8(const float* __restrict__ p) {
  const float4 a = *(const float4*)p;
  const float4 b = *(const float4*)(p + 4);
  short8 o;
  o[0]=(short)f2bf(a.x); o[1]=(short)f2bf(a.y); o[2]=(short)f2bf(a.z); o[3]=(short)f2bf(a.w);
  o[4]=(short)f2bf(b.x); o[5]=(short)f2bf(b.y); o[6]=(short)f2bf(b.z); o[7]=(short)f2bf(b.w);
  return o;
}

__device__ __forceinline__ void lse_online(float& m, float& s, float tt) {
  if (tt > m) { s = s * __expf(m - tt) + 1.f; m = tt; }
  else        { s += __expf(tt - m); }
}

// ---------------------------------------------------------------------------
// weight transpose + f32->bf16:  out[n*K+k] = bf16(W[k*N+n])
// ---------------------------------------------------------------------------
__global__ __launch_bounds__(256)
void wconv(const float* __restrict__ W, u16* __restrict__ out, int K, int N)
{
  const int i = blockIdx.x * 256 + threadIdx.x;
  if (i < K * N) {
    const int n = i / K, k = i - n * K;
    out[i] = f2bf(W[(size_t)k * N + n]);
  }
}

// ---------------------------------------------------------------------------
// MFMA fused 2-layer MLP, 32-row tiles, LDS union (sA aliases sH).
// h and agg are stored bf16 (rounding moved from read to write: identical
// numerics, half the gather bytes, no cvt chains in the staging hot path).
// IN_MODE: 1 [hb[IA],hb[IB],comb]  3 [hb,aggFb,aggBb]  4 [e(f32), inter(f32|0)]
// DUAL: also compute with first two 64-blocks swapped (k^64).
// OUT_MODE: 0 f32 write (sum)  1 bf16 write (sum)  2 bf16 per-dir -> Yb0/Yb1
// ---------------------------------------------------------------------------
template<int K1, int HID, int NOUT, int IN_MODE, int DUAL, int OUT_MODE>
__global__ __launch_bounds__(256, 4)
void mlp_mfma(const void* __restrict__ X, const void* __restrict__ P2,
              const void* __restrict__ P3, const u16* __restrict__ CB,
              const int* __restrict__ IA, const int* __restrict__ IB,
              const u16* __restrict__ W1t, const float* __restrict__ B1,
              const u16* __restrict__ W2t, const float* __restrict__ B2,
              float* __restrict__ Yf, u16* __restrict__ Yb0, u16* __restrict__ Yb1)
{
  constexpr int RT  = 32;
  constexpr int KCH = K1 / 8;
  constexpr int NT1 = HID / 64;
  constexpr int NT2 = (NOUT >= 64) ? NOUT / 64 : 1;
  constexpr int SAB = RT * K1 * 2;
  constexpr int SHB = RT * (HID + 8) * 2;
  __shared__ __align__(16) char smem[(SAB > SHB ? SAB : SHB)];
  u16* sA = (u16*)smem;
  u16* sH = (u16*)smem;

  const int tid = threadIdx.x;
  const int rowBase = blockIdx.x * RT;

  // ---- stage A panel, XOR-swizzled rows ----
  for (int ch = tid; ch < RT * KCH; ch += 256) {
    const int r = ch / KCH, kc = ch - r * KCH;
    const int gr = rowBase + r, k0 = kc * 8;
    short8 pk;
    if constexpr (IN_MODE == 4) {
      const float* Xf  = (const float*)X;
      const float* P2f = (const float*)P2;
      if (k0 < 128)      pk = cvt8(&Xf[(size_t)gr * 128 + k0]);
      else if (P2f)      pk = cvt8(&P2f[(size_t)gr * 128 + (k0 - 128)]);
      else { pk = short8{0,0,0,0,0,0,0,0}; }
    } else if constexpr (IN_MODE == 1) {
      const u16* Hb = (const u16*)X;
      if (k0 < 64)       pk = *(const short8*)&Hb[(size_t)IA[gr] * 64 + k0];
      else if (k0 < 128) pk = *(const short8*)&Hb[(size_t)IB[gr] * 64 + (k0 - 64)];
      else               pk = *(const short8*)&CB[(size_t)gr * 128 + (k0 - 128)];
    } else { // 3
      const u16* Hb = (const u16*)X;
      const u16* A0 = (const u16*)P2;
      const u16* A1 = (const u16*)P3;
      if (k0 < 64)       pk = *(const short8*)&Hb[(size_t)gr * 64 + k0];
      else if (k0 < 192) pk = *(const short8*)&A0[(size_t)gr * 128 + (k0 - 64)];
      else               pk = *(const short8*)&A1[(size_t)gr * 128 + (k0 - 192)];
    }
    const int byte = ((r * K1 + k0) * 2) ^ ((r & 7) << 4);
    *(short8*)((char*)sA + byte) = pk;
  }
  __syncthreads();

  const int wid = tid >> 6, lane = tid & 63;
  const int l15 = lane & 15, lg = lane >> 4;

  // ---- layer 1, all dirs (sA stays live only here) ----
  floatx4 acc1[1 + DUAL][2][NT1];
  #pragma unroll
  for (int d = 0; d <= DUAL; ++d)
    #pragma unroll
    for (int m = 0; m < 2; ++m)
      #pragma unroll
      for (int n = 0; n < NT1; ++n) acc1[d][m][n] = floatx4{0.f,0.f,0.f,0.f};

  #pragma unroll 2
  for (int kk = 0; kk < K1 / 32; ++kk) {
    short8 bw[NT1];
    #pragma unroll
    for (int n = 0; n < NT1; ++n) {
      const int col = wid * (HID / 4) + n * 16 + l15;
      bw[n] = *(const short8*)&W1t[(size_t)col * K1 + kk * 32 + lg * 8];
    }
    #pragma unroll
    for (int d = 0; d <= DUAL; ++d) {
      int k0 = kk * 32 + lg * 8;
      if (DUAL && d && k0 < 128) k0 ^= 64;
      #pragma unroll
      for (int m = 0; m < 2; ++m) {
        const int r = m * 16 + l15;
        const int byte = ((r * K1 + k0) * 2) ^ ((r & 7) << 4);
        const short8 af = *(const short8*)((char*)sA + byte);
        #pragma unroll
        for (int n = 0; n < NT1; ++n)
          acc1[d][m][n] = __builtin_amdgcn_mfma_f32_16x16x32_bf16(af, bw[n], acc1[d][m][n], 0, 0, 0);
      }
    }
  }
  __syncthreads();   // sA dead from here; smem becomes sH

  floatx4 accO[2][NT2];
  #pragma unroll
  for (int m = 0; m < 2; ++m)
    #pragma unroll
    for (int n = 0; n < NT2; ++n) accO[m][n] = floatx4{0.f,0.f,0.f,0.f};

  #pragma unroll
  for (int d = 0; d <= DUAL; ++d) {
    // hidden: bias + relu -> bf16 LDS
    #pragma unroll
    for (int n = 0; n < NT1; ++n) {
      const int col = wid * (HID / 4) + n * 16 + l15;
      const float b1 = B1[col];
      #pragma unroll
      for (int m = 0; m < 2; ++m)
        #pragma unroll
        for (int r = 0; r < 4; ++r) {
          const int row = m * 16 + lg * 4 + r;
          const float y = acc1[d][m][n][r] + b1;
          sH[row * (HID + 8) + col] = f2bf(y > 0.f ? y : 0.f);
        }
    }
    __syncthreads();
    if (OUT_MODE == 2 && d == 1) {
      #pragma unroll
      for (int m = 0; m < 2; ++m)
        #pragma unroll
        for (int n = 0; n < NT2; ++n) accO[m][n] = floatx4{0.f,0.f,0.f,0.f};
    }
    #pragma unroll 2
    for (int kk = 0; kk < HID / 32; ++kk) {
      short8 bw2[NT2];
      #pragma unroll
      for (int n = 0; n < NT2; ++n) {
        const int col = wid * (NOUT / 4) + n * 16 + l15;
        bw2[n] = *(const short8*)&W2t[(size_t)col * HID + kk * 32 + lg * 8];
      }
      #pragma unroll
      for (int m = 0; m < 2; ++m) {
        const short8 af = *(const short8*)&sH[(m * 16 + l15) * (HID + 8) + kk * 32 + lg * 8];
        #pragma unroll
        for (int n = 0; n < NT2; ++n)
          accO[m][n] = __builtin_amdgcn_mfma_f32_16x16x32_bf16(af, bw2[n], accO[m][n], 0, 0, 0);
      }
    }
    if constexpr (OUT_MODE == 2) {
      u16* Y = d ? Yb1 : Yb0;
      #pragma unroll
      for (int n = 0; n < NT2; ++n) {
        const int col = wid * (NOUT / 4) + n * 16 + l15;
        const float b2 = B2[col];
        #pragma unroll
        for (int m = 0; m < 2; ++m)
          #pragma unroll
          for (int r = 0; r < 4; ++r) {
            const int gr = rowBase + m * 16 + lg * 4 + r;
            Y[(size_t)gr * NOUT + col] = f2bf(accO[m][n][r] + b2);
          }
      }
    }
    if (DUAL && d == 0) __syncthreads();   // before overwriting sH
  }

  if constexpr (OUT_MODE != 2) {
    #pragma unroll
    for (int n = 0; n < NT2; ++n) {
      const int col = wid * (NOUT / 4) + n * 16 + l15;
      const float b2 = B2[col] * (float)(1 + DUAL);
      #pragma unroll
      for (int m = 0; m < 2; ++m)
        #pragma unroll
        for (int r = 0; r < 4; ++r) {
          const int gr = rowBase + m * 16 + lg * 4 + r;
          const float y = accO[m][n][r] + b2;
          if constexpr (OUT_MODE == 1) Yb0[(size_t)gr * NOUT + col] = f2bf(y);
          else                         Yf[(size_t)gr * NOUT + col] = y;
        }
    }
  }
}

// ---------------------------------------------------------------------------
// Pair-local segment-sum scatter: block = pair*2 + dir. Emits bf16 agg.
// ---------------------------------------------------------------------------
__global__ __launch_bounds__(256)
void scatter_agg(const u16* __restrict__ MF, const u16* __restrict__ MB,
                 const int* __restrict__ FI, const int* __restrict__ TI,
                 u16* __restrict__ AggF, u16* __restrict__ AggB)
{
  const int pair = blockIdx.x >> 1, dir = blockIdx.x & 1;
  const u16* M  = dir ? MB : MF;
  const int* SI = dir ? FI : TI;
  u16* Agg      = dir ? AggB : AggF;
  const int tid = threadIdx.x;
  __shared__ float sAgg[NPG * 128];

  for (int i = tid; i < NPG * 128; i += 256) sAgg[i] = 0.f;
  __syncthreads();

  for (int i = tid; i < EPG * 32; i += 256) {
    const int edge = i >> 5, cb = i & 31;
    const int er = pair * EPG + edge;
    const int node = SI[er] - pair * NPG;
    const size_t base = (size_t)er * 128 + cb;
    #pragma unroll
    for (int k = 0; k < 4; ++k)
      atomicAdd(&sAgg[node * 128 + cb + 32 * k], bf2f(M[base + 32 * k]));
  }
  __syncthreads();
  unsigned* dst = (unsigned*)(Agg + (size_t)pair * NPG * 128);
  for (int i = tid; i < NPG * 64; i += 256)
    dst[i] = pack2(sAgg[2 * i], sAgg[2 * i + 1]);
}

// ---------------------------------------------------------------------------
// f32 fused MLP (encoders + sinkhorn feature MLPs)
// IN_MODE: 0 plain X  5 q-side rows of e (zero-padded)  6 c-side rows
// OUTBF (SINGLE only): write bf16 to Yb
// ---------------------------------------------------------------------------
template<int K1, int HID, int NOUT, int IN_MODE, int SINGLE, int OUTBF>
__global__ __launch_bounds__(256)
void fused_mlp(const float* __restrict__ X, const float* __restrict__ P1,
               const float* __restrict__ W1, const float* __restrict__ B1,
               const float* __restrict__ W2, const float* __restrict__ B2,
               float* __restrict__ Y, u16* __restrict__ Yb, int maskLen)
{
  constexpr int RT = 32, BK = 32;
  constexpr int J1 = HID / 32;
  constexpr int J2 = NOUT / 32;
  constexpr int BMAX = (HID > NOUT ? HID : NOUT);
  __shared__ float sA[RT * 33];
  __shared__ float sB[BK * BMAX];
  __shared__ float sH[SINGLE ? 1 : RT * (HID + 1)];

  const int t  = threadIdx.x;
  const int tx = t & 31, ty = t >> 5;
  const int rowBase = blockIdx.x * RT;

  float acc[4][J1];
  #pragma unroll
  for (int i = 0; i < 4; ++i)
    #pragma unroll
    for (int j = 0; j < J1; ++j) acc[i][j] = 0.f;

  for (int kb = 0; kb < K1; kb += BK) {
    for (int l = t; l < RT * BK; l += 256) {
      const int r = l >> 5, k = l & 31;
      const int gr = rowBase + r, gk = kb + k;
      float v;
      if constexpr (IN_MODE == 0) {
        v = X[(size_t)gr * K1 + gk];
      } else {
        const int bb = gr >> 8, m = gr & 255;
        constexpr int off = (IN_MODE == 5) ? 0 : EQ_;
        constexpr int len = (IN_MODE == 5) ? EQ_ : EC_;
        v = (m < len) ? P1[((size_t)bb * EPG + off + m) * 128 + gk] : 0.f;
      }
      sA[r * 33 + k] = v;
    }
    for (int l = t * 4; l < BK * HID; l += 1024) {
      *(float4*)&sB[l] = *(const float4*)&W1[(size_t)(kb + l / HID) * HID + (l % HID)];
    }
    __syncthreads();
    #pragma unroll
    for (int k = 0; k < BK; ++k) {
      const float a0 = sA[(ty*4+0)*33+k], a1 = sA[(ty*4+1)*33+k],
                  a2 = sA[(ty*4+2)*33+k], a3 = sA[(ty*4+3)*33+k];
      #pragma unroll
      for (int j = 0; j < J1; ++j) {
        const float bb = sB[k * HID + tx + 32*j];
        acc[0][j] += a0 * bb; acc[1][j] += a1 * bb;
        acc[2][j] += a2 * bb; acc[3][j] += a3 * bb;
      }
    }
    __syncthreads();
  }

  if constexpr (SINGLE) {
    #pragma unroll
    for (int j = 0; j < J1; ++j) {
      const int col = tx + 32*j;
      const float bias = B1[col];
      #pragma unroll
      for (int i = 0; i < 4; ++i) {
        const int gr = rowBase + ty*4 + i;
        if constexpr (OUTBF) Yb[(size_t)gr * HID + col] = f2bf(acc[i][j] + bias);
        else                 Y[(size_t)gr * HID + col] = acc[i][j] + bias;
      }
    }
  } else {
    #pragma unroll
    for (int j = 0; j < J1; ++j) {
      const int col = tx + 32*j;
      const float bias = B1[col];
      #pragma unroll
      for (int i = 0; i < 4; ++i) {
        float y = acc[i][j] + bias;
        sH[(ty*4+i) * (HID+1) + col] = y > 0.f ? y : 0.f;
      }
    }
    __syncthreads();

    float acc2[4][J2];
    #pragma unroll
    for (int i = 0; i < 4; ++i)
      #pragma unroll
      for (int j = 0; j < J2; ++j) acc2[i][j] = 0.f;

    for (int kb = 0; kb < HID; kb += BK) {
      for (int l = t * 4; l < BK * NOUT; l += 1024) {
        *(float4*)&sB[l] = *(const float4*)&W2[(size_t)(kb + l / NOUT) * NOUT + (l % NOUT)];
      }
      __syncthreads();
      #pragma unroll
      for (int k = 0; k < BK; ++k) {
        const float a0 = sH[(ty*4+0)*(HID+1) + kb + k],
                    a1 = sH[(ty*4+1)*(HID+1) + kb + k],
                    a2 = sH[(ty*4+2)*(HID+1) + kb + k],
                    a3 = sH[(ty*4+3)*(HID+1) + kb + k];
        #pragma unroll
        for (int j = 0; j < J2; ++j) {
          const float bb = sB[k * NOUT + tx + 32*j];
          acc2[0][j] += a0 * bb; acc2[1][j] += a1 * bb;
          acc2[2][j] += a2 * bb; acc2[3][j] += a3 * bb;
        }
      }
      __syncthreads();
    }
    #pragma unroll
    for (int j = 0; j < J2; ++j) {
      const int col = tx + 32*j;
      const float bias = B2[col];
      #pragma unroll
      for (int i = 0; i < 4; ++i) {
        const int gr = rowBase + ty*4 + i;
        float y = acc2[i][j] + bias;
        if (maskLen >= 0 && (gr & 255) >= maskLen) y = 0.f;
        Y[(size_t)gr * NOUT + col] = y;
      }
    }
  }
}

// ---------------------------------------------------------------------------
// S[b] = scale * fq[b] @ fc[b]^T
// ---------------------------------------------------------------------------
__global__ __launch_bounds__(256)
void gemm_nt_scale(const float* __restrict__ A, const float* __restrict__ Bm,
                   float* __restrict__ C, float scale)
{
  const int b = blockIdx.z, qt = blockIdx.x, ct = blockIdx.y;
  __shared__ float sA[64 * 68];
  __shared__ float sB[64 * 68];
  const int t = threadIdx.x;
  const int tx = t & 15, ty = t >> 4;
  const float* Ab = A  + (size_t)b * 16384 + (size_t)qt * 4096;
  const float* Bb = Bm + (size_t)b * 16384 + (size_t)ct * 4096;
  for (int l = t * 4; l < 64 * 64; l += 1024) {
    const int r = l >> 6, d = l & 63;
    *(float4*)&sA[r*68 + d] = *(const float4*)&Ab[r*64 + d];
    *(float4*)&sB[r*68 + d] = *(const float4*)&Bb[r*64 + d];
  }
  __syncthreads();
  float acc[4][4] = {};
  #pragma unroll
  for (int d = 0; d < 64; ++d) {
    float a[4], bb[4];
    #pragma unroll
    for (int i = 0; i < 4; ++i) a[i]  = sA[(ty*4+i)*68 + d];
    #pragma unroll
    for (int j = 0; j < 4; ++j) bb[j] = sB[(tx+16*j)*68 + d];
    #pragma unroll
    for (int i = 0; i < 4; ++i)
      #pragma unroll
      for (int j = 0; j < 4; ++j) acc[i][j] += a[i] * bb[j];
  }
  float* Cb = C + (size_t)b * 65536 + (size_t)(qt*64) * 256 + ct*64;
  #pragma unroll
  for (int i = 0; i < 4; ++i)
    #pragma unroll
    for (int j = 0; j < 4; ++j)
      Cb[(ty*4+i)*256 + tx + 16*j] = acc[i][j] * scale;
}

// ---------------------------------------------------------------------------
// Y rows r<maskRows at ((b*RPB + YOFF + r)*128) = op(P[b]) @ V (gathered from e)
// ---------------------------------------------------------------------------
template<int TRANSA>
__global__ __launch_bounds__(256)
void gemm_plan(const float* __restrict__ P, const float* __restrict__ E,
               float* __restrict__ Y, int RPB, int YOFF, int VOFF, int VLEN,
               int maskRows)
{
  const int b = blockIdx.y, rt = blockIdx.x;
  __shared__ float sA[64 * 33];
  __shared__ float sB[32 * 128];
  const int t = threadIdx.x;
  const int tx = t & 15, ty = t >> 4;
  const float* Pb = P + (size_t)b * 65536;
  float acc[4][8] = {};
  for (int kb = 0; kb < 256; kb += 32) {
    if constexpr (TRANSA == 0) {
      for (int l = t; l < 64 * 32; l += 256) {
        const int r = l >> 5, k = l & 31;
        sA[r*33 + k] = Pb[(size_t)(rt*64 + r) * 256 + kb + k];
      }
    } else {
      for (int l = t; l < 64 * 32; l += 256) {
        const int r = l & 63, k = l >> 6;
        sA[r*33 + k] = Pb[(size_t)(kb + k) * 256 + rt*64 + r];
      }
    }
    for (int l = t * 4; l < 32 * 128; l += 1024) {
      const int vr = kb + (l >> 7), d = l & 127;
      float4 val = {0.f, 0.f, 0.f, 0.f};
      if (vr < VLEN) val = *(const float4*)&E[((size_t)b * EPG + VOFF + vr) * 128 + d];
      *(float4*)&sB[l] = val;
    }
    __syncthreads();
    #pragma unroll
    for (int k = 0; k < 32; ++k) {
      float a[4], bb[8];
      #pragma unroll
      for (int i = 0; i < 4; ++i) a[i]  = sA[(ty*4+i)*33 + k];
      #pragma unroll
      for (int j = 0; j < 8; ++j) bb[j] = sB[k*128 + tx + 16*j];
      #pragma unroll
      for (int i = 0; i < 4; ++i)
        #pragma unroll
        for (int j = 0; j < 8; ++j) acc[i][j] += a[i] * bb[j];
    }
    __syncthreads();
  }
  #pragma unroll
  for (int i = 0; i < 4; ++i) {
    const int r = rt*64 + ty*4 + i;
    if (r >= maskRows) continue;
    float* yr = Y + ((size_t)b * RPB + YOFF + r) * 128;
    #pragma unroll
    for (int j = 0; j < 8; ++j) yr[tx + 16*j] = acc[i][j];
  }
}

// ---------------------------------------------------------------------------
// Single-pass fused sinkhorn with exp-free butterflies (round-11 proven).
// ---------------------------------------------------------------------------
__global__ __launch_bounds__(1024)
void sinkhorn_fused(float* __restrict__ S)
{
  const int b = blockIdx.x, t = threadIdx.x;
  float* Sb = S + (size_t)b * 65536;
  const int w = t >> 6, lane = t & 63;
  const int cbase = lane * 4;
  __shared__ float pm[16 * 256], ps[16 * 256];
  __shared__ float su[256], sv[256];
  if (t < 256) sv[t] = 0.f;
  __syncthreads();

  for (int it = 0; it < 10; ++it) {
    const float4 v4 = *(const float4*)&sv[cbase];
    float4 cm = {-1e30f, -1e30f, -1e30f, -1e30f};
    float4 cs = {0.f, 0.f, 0.f, 0.f};
    #pragma unroll 2
    for (int i = 0; i < 16; ++i) {
      const int r = w * 16 + i;
      const float4 s4 = *(const float4*)&Sb[(size_t)r * 256 + cbase];
      const float ax = s4.x + v4.x, ay = s4.y + v4.y;
      const float az = s4.z + v4.z, aw = s4.w + v4.w;
      float m = fmaxf(fmaxf(ax, ay), fmaxf(az, aw));
      #pragma unroll
      for (int off = 32; off; off >>= 1) m = fmaxf(m, __shfl_xor(m, off));
      float s = __expf(ax - m) + __expf(ay - m) + __expf(az - m) + __expf(aw - m);
      #pragma unroll
      for (int off = 32; off; off >>= 1) s += __shfl_xor(s, off);
      const float u = -(m + __logf(s));
      if (lane == 0) su[r] = u;
      lse_online(cm.x, cs.x, s4.x + u);
      lse_online(cm.y, cs.y, s4.y + u);
      lse_online(cm.z, cs.z, s4.z + u);
      lse_online(cm.w, cs.w, s4.w + u);
    }
    *(float4*)&pm[w * 256 + cbase] = cm;
    *(float4*)&ps[w * 256 + cbase] = cs;
    __syncthreads();
    if (t < 256) {
      float m = pm[t];
      #pragma unroll
      for (int k = 1; k < 16; ++k) m = fmaxf(m, pm[k * 256 + t]);
      float s = 0.f;
      #pragma unroll
      for (int k = 0; k < 16; ++k) s += ps[k * 256 + t] * __expf(pm[k * 256 + t] - m);
      sv[t] = -(m + __logf(s));
    }
    __syncthreads();
  }
  for (int i = t; i < 16384; i += 1024) {
    const int row = i >> 6, c4 = (i & 63) * 4;
    float4 s4 = *(float4*)&Sb[(size_t)row * 256 + c4];
    const float uu = su[row];
    const float4 v4 = *(const float4*)&sv[c4];
    s4.x = __expf(s4.x + uu + v4.x);
    s4.y = __expf(s4.y + uu + v4.y);
    s4.z = __expf(s4.z + uu + v4.z);
    s4.w = __expf(s4.w + uu + v4.w);
    *(float4*)&Sb[(size_t)row * 256 + c4] = s4;
  }
}

// ---------------------------------------------------------------------------
// score[b] = -sum_{m<256,d} | (m<EQ ? e_q[m,d] : 0) - pc[m,d] |
// ---------------------------------------------------------------------------
__global__ __launch_bounds__(256)
void escore_kernel(const float* __restrict__ e, const float* __restrict__ pc,
                   float* __restrict__ out)
{
  const int b = blockIdx.x, t = threadIdx.x;
  float acc = 0.f;
  for (int i4 = t; i4 < 8192; i4 += 256) {
    const int flat = i4 * 4;
    const int m = flat >> 7, d = flat & 127;
    float4 p = *(const float4*)&pc[((size_t)b * 256 + m) * 128 + d];
    float4 q = {0.f, 0.f, 0.f, 0.f};
    if (m < EQ_) q = *(const float4*)&e[((size_t)b * EPG + m) * 128 + d];
    acc += fabsf(q.x - p.x) + fabsf(q.y - p.y) + fabsf(q.z - p.z) + fabsf(q.w - p.w);
  }
  __shared__ float red[256];
  red[t] = acc; __syncthreads();
  for (int s2 = 128; s2 > 0; s2 >>= 1) { if (t < s2) red[t] += red[t + s2]; __syncthreads(); }
  if (t == 0) out[b] = -red[0];
}

// ---------------------------------------------------------------------------
extern "C" void kernel_launch(void* const* d_in, const int* in_sizes, int n_in,
                              void* d_out, int out_size, void* d_ws, size_t ws_size,
                              hipStream_t stream)
{
  const float* node_features = (const float*)d_in[0];
  const float* edge_features = (const float*)d_in[1];
  const int*   from_idx      = (const int*)d_in[2];
  const int*   to_idx        = (const int*)d_in[3];
  const float* enc_node_W = (const float*)d_in[4];
  const float* enc_node_b = (const float*)d_in[5];
  const float* enc_edge_W = (const float*)d_in[6];
  const float* enc_edge_b = (const float*)d_in[7];
  const float* msg_W1 = (const float*)d_in[8];
  const float* msg_b1 = (const float*)d_in[9];
  const float* msg_W2 = (const float*)d_in[10];
  const float* msg_b2 = (const float*)d_in[11];
  const float* upd_W1 = (const float*)d_in[12];
  const float* upd_b1 = (const float*)d_in[13];
  const float* upd_W2 = (const float*)d_in[14];
  const float* upd_b2 = (const float*)d_in[15];
  const float* int_W1 = (const float*)d_in[16];
  const float* int_b1 = (const float*)d_in[17];
  const float* int_W2 = (const float*)d_in[18];
  const float* int_b2 = (const float*)d_in[19];
  const float* sink_W1 = (const float*)d_in[20];
  const float* sink_b1 = (const float*)d_in[21];
  const float* sink_W2 = (const float*)d_in[22];
  const float* sink_b2 = (const float*)d_in[23];
  float* out = (float*)d_out;

  // ~224 MB layout (proven). h now bf16 (in its old f32-sized region);
  // aggF/aggB now bf16 inside shr. mf/mb bf16 alias e's dead window.
  float* wsf = (float*)d_ws;
  float* hreg = wsf;                              // region: NN*64 f32-sized
  float* e   = hreg + (size_t)NN * 64;            // NE*128 f32
  float* shr = e + (size_t)NE * 128;              // NE*128 f32 (inter | agg bf16 | fq+fc | pc)
  float* S   = shr + (size_t)NE * 128;            // BATCH*65536 f32
  u16* comb  = (u16*)(S + (size_t)BATCH * 65536); // NE*128 bf16
  u16* wi1 = comb + (size_t)NE * 128;             // 256x256
  u16* wi2 = wi1 + 65536;                         // 128x256
  u16* wm1 = wi2 + 32768;                         // 256x256
  u16* wm2 = wm1 + 65536;                         // 128x256
  u16* wu1 = wm2 + 32768;                         // 128x320
  u16* wu2 = wu1 + 40960;                         // 64x128

  u16* hb  = (u16*)hreg;                          // NN*64 bf16 node states
  u16* mfb = (u16*)e;                             // aliases e (dead window)
  u16* mbb = mfb + (size_t)NE * 128;

  u16* aggFb = (u16*)shr;                         // NN*128 bf16
  u16* aggBb = aggFb + (size_t)NN * 128;
  float* inter = shr;                             // EPG-row layout (f32)
  float* fq    = shr;
  float* fc    = shr + (size_t)BATCH * 16384;

  // weights -> bf16, transposed [N][K]
  wconv<<<256, 256, 0, stream>>>(int_W1, wi1, 256, 256);
  wconv<<<128, 256, 0, stream>>>(int_W2, wi2, 256, 128);
  wconv<<<256, 256, 0, stream>>>(msg_W1, wm1, 256, 256);
  wconv<<<128, 256, 0, stream>>>(msg_W2, wm2, 256, 128);
  wconv<<<160, 256, 0, stream>>>(upd_W1, wu1, 320, 128);
  wconv<<< 32, 256, 0, stream>>>(upd_W2, wu2, 128, 64);

  for (int ts = 0; ts < 2; ++ts) {
    // encoders (reset hb, e)
    fused_mlp<32,64,64,0,1,1><<<NN/32, 256, 0, stream>>>(
        node_features, nullptr, enc_node_W, enc_node_b, nullptr, nullptr,
        nullptr, hb, -1);
    fused_mlp<32,128,128,0,1,0><<<NE/32, 256, 0, stream>>>(
        edge_features, nullptr, enc_edge_W, enc_edge_b, nullptr, nullptr,
        e, nullptr, -1);

    for (int p = 0; p < 3; ++p) {
      // comb = intMLP([e, inter]) -> bf16   (inter==0 for ts0 and ts1/p0)
      const float* interArg = (ts == 1 && p > 0) ? inter : nullptr;
      mlp_mfma<256,256,128,4,0,1><<<NE/32, 256, 0, stream>>>(
          e, interArg, nullptr, nullptr, nullptr, nullptr,
          wi1, int_b1, wi2, int_b2, nullptr, comb, nullptr);
      // messages on old h -> mf, mb (bf16, in e's dead storage), both dirs
      mlp_mfma<256,256,128,1,1,2><<<NE/32, 256, 0, stream>>>(
          hb, nullptr, nullptr, comb, from_idx, to_idx,
          wm1, msg_b1, wm2, msg_b2, nullptr, mfb, mbb);
      // pair-local segment sums (LDS), both dirs as blocks -> bf16 agg
      scatter_agg<<<BATCH*2, 256, 0, stream>>>(mfb, mbb, from_idx, to_idx, aggFb, aggBb);
      // node update (in place, bf16)
      mlp_mfma<320,128,64,3,0,1><<<NN/32, 256, 0, stream>>>(
          hb, aggFb, aggBb, nullptr, nullptr, nullptr,
          wu1, upd_b1, wu2, upd_b2, nullptr, hb, nullptr);
      // e = mf2 + mb2 with updated h (dual-direction sum; overwrites mf/mb)
      mlp_mfma<256,256,128,1,1,0><<<NE/32, 256, 0, stream>>>(
          hb, nullptr, nullptr, comb, from_idx, to_idx,
          wm1, msg_b1, wm2, msg_b2, e, nullptr, nullptr);
      // interaction features from last time step's transport plan
      if (ts == 1 && p < 2) {
        gemm_plan<0><<<dim3(4, BATCH), 256, 0, stream>>>(
            S, e, inter, EPG, 0,   EQ_, EC_, EQ_);
        gemm_plan<1><<<dim3(4, BATCH), 256, 0, stream>>>(
            S, e, inter, EPG, EQ_, 0,   EQ_, EC_);
      }
    }
    // sinkhorn features + plan
    fused_mlp<128,64,64,5,0,0><<<BATCH*8, 256, 0, stream>>>(
        nullptr, e, sink_W1, sink_b1, sink_W2, sink_b2, fq, nullptr, EQ_);
    fused_mlp<128,64,64,6,0,0><<<BATCH*8, 256, 0, stream>>>(
        nullptr, e, sink_W1, sink_b1, sink_W2, sink_b2, fc, nullptr, EC_);
    gemm_nt_scale<<<dim3(4,4,BATCH), 256, 0, stream>>>(fq, fc, S, 10.0f);
    sinkhorn_fused<<<BATCH, 1024, 0, stream>>>(S);   // S := plan
  }

  // final score
  gemm_plan<0><<<dim3(4, BATCH), 256, 0, stream>>>(S, e, shr, 256, 0, EQ_, EC_, 256);
  escore_kernel<<<BATCH, 256, 0, stream>>>(e, shr, out);
}

// Round 13
// 4181.700 us; speedup vs baseline: 1.1923x; 1.0281x over previous
//
#include <hip/hip_runtime.h>
#include <math.h>

constexpr int BATCH = 256;
constexpr int EQ_   = 192;
constexpr int EC_   = 240;
constexpr int EPG   = 432;   // edges per pair
constexpr int NPG   = 216;   // nodes per pair
constexpr int NN    = BATCH * NPG;   // 55296
constexpr int NE    = BATCH * EPG;   // 110592

typedef __attribute__((ext_vector_type(8))) short short8;
typedef __attribute__((ext_vector_type(4))) float floatx4;
typedef unsigned short u16;

__device__ __forceinline__ u16 f2bf(float x) {
  union { float f; unsigned u; } c; c.f = x;
  const unsigned r = (c.u + 0x7FFFu + ((c.u >> 16) & 1u)) >> 16;
  return (u16)r;
}
__device__ __forceinline__ float bf2f(u16 x) {
  union { unsigned u; float f; } c; c.u = ((unsigned)x) << 16;
  return c.f;
}
__device__ __forceinline__ unsigned pack2(float a, float b) {
  return (unsigned)f2bf(a) | ((unsigned)f2bf(b) << 16);
}
__device__ __forceinline__ short8 cvt8(const float* __restrict__ p) {
  const float4 a = *(const float4*)p;
  const float4 b = *(const float4*)(p + 4);
  short8 o;
  o[0]=(short)f2bf(a.x); o[1]=(short)f2bf(a.y); o[2]=(short)f2bf(a.z); o[3]=(short)f2bf(a.w);
  o[4]=(short)f2bf(b.x); o[5]=(short)f2bf(b.y); o[6]=(short)f2bf(b.z); o[7]=(short)f2bf(b.w);
  return o;
}

__device__ __forceinline__ void lse_online(float& m, float& s, float tt) {
  if (tt > m) { s = s * __expf(m - tt) + 1.f; m = tt; }
  else        { s += __expf(tt - m); }
}

// ---------------------------------------------------------------------------
// weight transpose + f32->bf16:  out[n*K+k] = bf16(W[k*N+n])
// ---------------------------------------------------------------------------
__global__ __launch_bounds__(256)
void wconv(const float* __restrict__ W, u16* __restrict__ out, int K, int N)
{
  const int i = blockIdx.x * 256 + threadIdx.x;
  if (i < K * N) {
    const int n = i / K, k = i - n * K;
    out[i] = f2bf(W[(size_t)k * N + n]);
  }
}

// ---------------------------------------------------------------------------
// MFMA fused 2-layer MLP, 32-row tiles, LDS union (sA aliases sH).
// WAVES template: 8-wave (512-thread) variant for the big edge MLPs halves
// per-wave accumulators (acc1 [2][2][2] vs [2][2][4]) -> VGPR < 128 ->
// 4 waves/SIMD occupancy tier (rounds 3/7-9: launch_bounds 2nd arg is
// ignored by this toolchain, so VGPR must be cut structurally).
// Work per wave, MFMA count, and all rounding points are unchanged.
// IN_MODE: 1 [hb[IA],hb[IB],comb]  3 [hb,aggFb,aggBb]  4 [e(f32), inter(f32|0)]
// OUT_MODE: 0 f32 write (sum)  1 bf16 write (sum)  2 bf16 per-dir -> Yb0/Yb1
// ---------------------------------------------------------------------------
template<int K1, int HID, int NOUT, int IN_MODE, int DUAL, int OUT_MODE, int WAVES>
__global__ __launch_bounds__(WAVES * 64, 4)
void mlp_mfma(const void* __restrict__ X, const void* __restrict__ P2,
              const void* __restrict__ P3, const u16* __restrict__ CB,
              const int* __restrict__ IA, const int* __restrict__ IB,
              const u16* __restrict__ W1t, const float* __restrict__ B1,
              const u16* __restrict__ W2t, const float* __restrict__ B2,
              float* __restrict__ Yf, u16* __restrict__ Yb0, u16* __restrict__ Yb1)
{
  constexpr int RT  = 32;
  constexpr int THREADS = WAVES * 64;
  constexpr int KCH = K1 / 8;
  constexpr int NT1 = HID / (WAVES * 16);
  constexpr int NT2 = (NOUT / (WAVES * 16) > 0) ? NOUT / (WAVES * 16) : 1;
  constexpr int SAB = RT * K1 * 2;
  constexpr int SHB = RT * (HID + 8) * 2;
  __shared__ __align__(16) char smem[(SAB > SHB ? SAB : SHB)];
  u16* sA = (u16*)smem;
  u16* sH = (u16*)smem;

  const int tid = threadIdx.x;
  const int rowBase = blockIdx.x * RT;

  // ---- stage A panel, XOR-swizzled rows ----
  for (int ch = tid; ch < RT * KCH; ch += THREADS) {
    const int r = ch / KCH, kc = ch - r * KCH;
    const int gr = rowBase + r, k0 = kc * 8;
    short8 pk;
    if constexpr (IN_MODE == 4) {
      const float* Xf  = (const float*)X;
      const float* P2f = (const float*)P2;
      if (k0 < 128)      pk = cvt8(&Xf[(size_t)gr * 128 + k0]);
      else if (P2f)      pk = cvt8(&P2f[(size_t)gr * 128 + (k0 - 128)]);
      else { pk = short8{0,0,0,0,0,0,0,0}; }
    } else if constexpr (IN_MODE == 1) {
      const u16* Hb = (const u16*)X;
      if (k0 < 64)       pk = *(const short8*)&Hb[(size_t)IA[gr] * 64 + k0];
      else if (k0 < 128) pk = *(const short8*)&Hb[(size_t)IB[gr] * 64 + (k0 - 64)];
      else               pk = *(const short8*)&CB[(size_t)gr * 128 + (k0 - 128)];
    } else { // 3
      const u16* Hb = (const u16*)X;
      const u16* A0 = (const u16*)P2;
      const u16* A1 = (const u16*)P3;
      if (k0 < 64)       pk = *(const short8*)&Hb[(size_t)gr * 64 + k0];
      else if (k0 < 192) pk = *(const short8*)&A0[(size_t)gr * 128 + (k0 - 64)];
      else               pk = *(const short8*)&A1[(size_t)gr * 128 + (k0 - 192)];
    }
    const int byte = ((r * K1 + k0) * 2) ^ ((r & 7) << 4);
    *(short8*)((char*)sA + byte) = pk;
  }
  __syncthreads();

  const int wid = tid >> 6, lane = tid & 63;
  const int l15 = lane & 15, lg = lane >> 4;

  // ---- layer 1, all dirs (sA stays live only here) ----
  floatx4 acc1[1 + DUAL][2][NT1];
  #pragma unroll
  for (int d = 0; d <= DUAL; ++d)
    #pragma unroll
    for (int m = 0; m < 2; ++m)
      #pragma unroll
      for (int n = 0; n < NT1; ++n) acc1[d][m][n] = floatx4{0.f,0.f,0.f,0.f};

  #pragma unroll 2
  for (int kk = 0; kk < K1 / 32; ++kk) {
    short8 bw[NT1];
    #pragma unroll
    for (int n = 0; n < NT1; ++n) {
      const int col = wid * (HID / WAVES) + n * 16 + l15;
      bw[n] = *(const short8*)&W1t[(size_t)col * K1 + kk * 32 + lg * 8];
    }
    #pragma unroll
    for (int d = 0; d <= DUAL; ++d) {
      int k0 = kk * 32 + lg * 8;
      if (DUAL && d && k0 < 128) k0 ^= 64;
      #pragma unroll
      for (int m = 0; m < 2; ++m) {
        const int r = m * 16 + l15;
        const int byte = ((r * K1 + k0) * 2) ^ ((r & 7) << 4);
        const short8 af = *(const short8*)((char*)sA + byte);
        #pragma unroll
        for (int n = 0; n < NT1; ++n)
          acc1[d][m][n] = __builtin_amdgcn_mfma_f32_16x16x32_bf16(af, bw[n], acc1[d][m][n], 0, 0, 0);
      }
    }
  }
  __syncthreads();   // sA dead from here; smem becomes sH

  floatx4 accO[2][NT2];
  #pragma unroll
  for (int m = 0; m < 2; ++m)
    #pragma unroll
    for (int n = 0; n < NT2; ++n) accO[m][n] = floatx4{0.f,0.f,0.f,0.f};

  #pragma unroll
  for (int d = 0; d <= DUAL; ++d) {
    // hidden: bias + relu -> bf16 LDS
    #pragma unroll
    for (int n = 0; n < NT1; ++n) {
      const int col = wid * (HID / WAVES) + n * 16 + l15;
      const float b1 = B1[col];
      #pragma unroll
      for (int m = 0; m < 2; ++m)
        #pragma unroll
        for (int r = 0; r < 4; ++r) {
          const int row = m * 16 + lg * 4 + r;
          const float y = acc1[d][m][n][r] + b1;
          sH[row * (HID + 8) + col] = f2bf(y > 0.f ? y : 0.f);
        }
    }
    __syncthreads();
    if (OUT_MODE == 2 && d == 1) {
      #pragma unroll
      for (int m = 0; m < 2; ++m)
        #pragma unroll
        for (int n = 0; n < NT2; ++n) accO[m][n] = floatx4{0.f,0.f,0.f,0.f};
    }
    #pragma unroll 2
    for (int kk = 0; kk < HID / 32; ++kk) {
      short8 bw2[NT2];
      #pragma unroll
      for (int n = 0; n < NT2; ++n) {
        const int col = wid * (NOUT / WAVES) + n * 16 + l15;
        bw2[n] = *(const short8*)&W2t[(size_t)col * HID + kk * 32 + lg * 8];
      }
      #pragma unroll
      for (int m = 0; m < 2; ++m) {
        const short8 af = *(const short8*)&sH[(m * 16 + l15) * (HID + 8) + kk * 32 + lg * 8];
        #pragma unroll
        for (int n = 0; n < NT2; ++n)
          accO[m][n] = __builtin_amdgcn_mfma_f32_16x16x32_bf16(af, bw2[n], accO[m][n], 0, 0, 0);
      }
    }
    if constexpr (OUT_MODE == 2) {
      u16* Y = d ? Yb1 : Yb0;
      #pragma unroll
      for (int n = 0; n < NT2; ++n) {
        const int col = wid * (NOUT / WAVES) + n * 16 + l15;
        const float b2 = B2[col];
        #pragma unroll
        for (int m = 0; m < 2; ++m)
          #pragma unroll
          for (int r = 0; r < 4; ++r) {
            const int gr = rowBase + m * 16 + lg * 4 + r;
            Y[(size_t)gr * NOUT + col] = f2bf(accO[m][n][r] + b2);
          }
      }
    }
    if (DUAL && d == 0) __syncthreads();   // before overwriting sH
  }

  if constexpr (OUT_MODE != 2) {
    #pragma unroll
    for (int n = 0; n < NT2; ++n) {
      const int col = wid * (NOUT / WAVES) + n * 16 + l15;
      const float b2 = B2[col] * (float)(1 + DUAL);
      #pragma unroll
      for (int m = 0; m < 2; ++m)
        #pragma unroll
        for (int r = 0; r < 4; ++r) {
          const int gr = rowBase + m * 16 + lg * 4 + r;
          const float y = accO[m][n][r] + b2;
          if constexpr (OUT_MODE == 1) Yb0[(size_t)gr * NOUT + col] = f2bf(y);
          else                         Yf[(size_t)gr * NOUT + col] = y;
        }
    }
  }
}

// ---------------------------------------------------------------------------
// Pair-local segment-sum scatter: block = pair*2 + dir, 512 threads.
// ---------------------------------------------------------------------------
__global__ __launch_bounds__(512)
void scatter_agg(const u16* __restrict__ MF, const u16* __restrict__ MB,
                 const int* __restrict__ FI, const int* __restrict__ TI,
                 u16* __restrict__ AggF, u16* __restrict__ AggB)
{
  const int pair = blockIdx.x >> 1, dir = blockIdx.x & 1;
  const u16* M  = dir ? MB : MF;
  const int* SI = dir ? FI : TI;
  u16* Agg      = dir ? AggB : AggF;
  const int tid = threadIdx.x;
  __shared__ float sAgg[NPG * 128];

  for (int i = tid; i < NPG * 128; i += 512) sAgg[i] = 0.f;
  __syncthreads();

  for (int i = tid; i < EPG * 32; i += 512) {
    const int edge = i >> 5, cb = i & 31;
    const int er = pair * EPG + edge;
    const int node = SI[er] - pair * NPG;
    const size_t base = (size_t)er * 128 + cb;
    #pragma unroll
    for (int k = 0; k < 4; ++k)
      atomicAdd(&sAgg[node * 128 + cb + 32 * k], bf2f(M[base + 32 * k]));
  }
  __syncthreads();
  unsigned* dst = (unsigned*)(Agg + (size_t)pair * NPG * 128);
  for (int i = tid; i < NPG * 64; i += 512)
    dst[i] = pack2(sAgg[2 * i], sAgg[2 * i + 1]);
}

// ---------------------------------------------------------------------------
// f32 fused MLP (encoders + sinkhorn feature MLPs)
// IN_MODE: 0 plain X  5 q-side rows of e (zero-padded)  6 c-side rows
// OUTBF (SINGLE only): write bf16 to Yb
// ---------------------------------------------------------------------------
template<int K1, int HID, int NOUT, int IN_MODE, int SINGLE, int OUTBF>
__global__ __launch_bounds__(256)
void fused_mlp(const float* __restrict__ X, const float* __restrict__ P1,
               const float* __restrict__ W1, const float* __restrict__ B1,
               const float* __restrict__ W2, const float* __restrict__ B2,
               float* __restrict__ Y, u16* __restrict__ Yb, int maskLen)
{
  constexpr int RT = 32, BK = 32;
  constexpr int J1 = HID / 32;
  constexpr int J2 = NOUT / 32;
  constexpr int BMAX = (HID > NOUT ? HID : NOUT);
  __shared__ float sA[RT * 33];
  __shared__ float sB[BK * BMAX];
  __shared__ float sH[SINGLE ? 1 : RT * (HID + 1)];

  const int t  = threadIdx.x;
  const int tx = t & 31, ty = t >> 5;
  const int rowBase = blockIdx.x * RT;

  float acc[4][J1];
  #pragma unroll
  for (int i = 0; i < 4; ++i)
    #pragma unroll
    for (int j = 0; j < J1; ++j) acc[i][j] = 0.f;

  for (int kb = 0; kb < K1; kb += BK) {
    for (int l = t; l < RT * BK; l += 256) {
      const int r = l >> 5, k = l & 31;
      const int gr = rowBase + r, gk = kb + k;
      float v;
      if constexpr (IN_MODE == 0) {
        v = X[(size_t)gr * K1 + gk];
      } else {
        const int bb = gr >> 8, m = gr & 255;
        constexpr int off = (IN_MODE == 5) ? 0 : EQ_;
        constexpr int len = (IN_MODE == 5) ? EQ_ : EC_;
        v = (m < len) ? P1[((size_t)bb * EPG + off + m) * 128 + gk] : 0.f;
      }
      sA[r * 33 + k] = v;
    }
    for (int l = t * 4; l < BK * HID; l += 1024) {
      *(float4*)&sB[l] = *(const float4*)&W1[(size_t)(kb + l / HID) * HID + (l % HID)];
    }
    __syncthreads();
    #pragma unroll
    for (int k = 0; k < BK; ++k) {
      const float a0 = sA[(ty*4+0)*33+k], a1 = sA[(ty*4+1)*33+k],
                  a2 = sA[(ty*4+2)*33+k], a3 = sA[(ty*4+3)*33+k];
      #pragma unroll
      for (int j = 0; j < J1; ++j) {
        const float bb = sB[k * HID + tx + 32*j];
        acc[0][j] += a0 * bb; acc[1][j] += a1 * bb;
        acc[2][j] += a2 * bb; acc[3][j] += a3 * bb;
      }
    }
    __syncthreads();
  }

  if constexpr (SINGLE) {
    #pragma unroll
    for (int j = 0; j < J1; ++j) {
      const int col = tx + 32*j;
      const float bias = B1[col];
      #pragma unroll
      for (int i = 0; i < 4; ++i) {
        const int gr = rowBase + ty*4 + i;
        if constexpr (OUTBF) Yb[(size_t)gr * HID + col] = f2bf(acc[i][j] + bias);
        else                 Y[(size_t)gr * HID + col] = acc[i][j] + bias;
      }
    }
  } else {
    #pragma unroll
    for (int j = 0; j < J1; ++j) {
      const int col = tx + 32*j;
      const float bias = B1[col];
      #pragma unroll
      for (int i = 0; i < 4; ++i) {
        float y = acc[i][j] + bias;
        sH[(ty*4+i) * (HID+1) + col] = y > 0.f ? y : 0.f;
      }
    }
    __syncthreads();

    float acc2[4][J2];
    #pragma unroll
    for (int i = 0; i < 4; ++i)
      #pragma unroll
      for (int j = 0; j < J2; ++j) acc2[i][j] = 0.f;

    for (int kb = 0; kb < HID; kb += BK) {
      for (int l = t * 4; l < BK * NOUT; l += 1024) {
        *(float4*)&sB[l] = *(const float4*)&W2[(size_t)(kb + l / NOUT) * NOUT + (l % NOUT)];
      }
      __syncthreads();
      #pragma unroll
      for (int k = 0; k < BK; ++k) {
        const float a0 = sH[(ty*4+0)*(HID+1) + kb + k],
                    a1 = sH[(ty*4+1)*(HID+1) + kb + k],
                    a2 = sH[(ty*4+2)*(HID+1) + kb + k],
                    a3 = sH[(ty*4+3)*(HID+1) + kb + k];
        #pragma unroll
        for (int j = 0; j < J2; ++j) {
          const float bb = sB[k * NOUT + tx + 32*j];
          acc2[0][j] += a0 * bb; acc2[1][j] += a1 * bb;
          acc2[2][j] += a2 * bb; acc2[3][j] += a3 * bb;
        }
      }
      __syncthreads();
    }
    #pragma unroll
    for (int j = 0; j < J2; ++j) {
      const int col = tx + 32*j;
      const float bias = B2[col];
      #pragma unroll
      for (int i = 0; i < 4; ++i) {
        const int gr = rowBase + ty*4 + i;
        float y = acc2[i][j] + bias;
        if (maskLen >= 0 && (gr & 255) >= maskLen) y = 0.f;
        Y[(size_t)gr * NOUT + col] = y;
      }
    }
  }
}

// ---------------------------------------------------------------------------
// S[b] = scale * fq[b] @ fc[b]^T
// ---------------------------------------------------------------------------
__global__ __launch_bounds__(256)
void gemm_nt_scale(const float* __restrict__ A, const float* __restrict__ Bm,
                   float* __restrict__ C, float scale)
{
  const int b = blockIdx.z, qt = blockIdx.x, ct = blockIdx.y;
  __shared__ float sA[64 * 68];
  __shared__ float sB[64 * 68];
  const int t = threadIdx.x;
  const int tx = t & 15, ty = t >> 4;
  const float* Ab = A  + (size_t)b * 16384 + (size_t)qt * 4096;
  const float* Bb = Bm + (size_t)b * 16384 + (size_t)ct * 4096;
  for (int l = t * 4; l < 64 * 64; l += 1024) {
    const int r = l >> 6, d = l & 63;
    *(float4*)&sA[r*68 + d] = *(const float4*)&Ab[r*64 + d];
    *(float4*)&sB[r*68 + d] = *(const float4*)&Bb[r*64 + d];
  }
  __syncthreads();
  float acc[4][4] = {};
  #pragma unroll
  for (int d = 0; d < 64; ++d) {
    float a[4], bb[4];
    #pragma unroll
    for (int i = 0; i < 4; ++i) a[i]  = sA[(ty*4+i)*68 + d];
    #pragma unroll
    for (int j = 0; j < 4; ++j) bb[j] = sB[(tx+16*j)*68 + d];
    #pragma unroll
    for (int i = 0; i < 4; ++i)
      #pragma unroll
      for (int j = 0; j < 4; ++j) acc[i][j] += a[i] * bb[j];
  }
  float* Cb = C + (size_t)b * 65536 + (size_t)(qt*64) * 256 + ct*64;
  #pragma unroll
  for (int i = 0; i < 4; ++i)
    #pragma unroll
    for (int j = 0; j < 4; ++j)
      Cb[(ty*4+i)*256 + tx + 16*j] = acc[i][j] * scale;
}

// ---------------------------------------------------------------------------
// Y rows r<maskRows at ((b*RPB + YOFF + r)*128) = op(P[b]) @ V (gathered from e)
// ---------------------------------------------------------------------------
template<int TRANSA>
__global__ __launch_bounds__(256)
void gemm_plan(const float* __restrict__ P, const float* __restrict__ E,
               float* __restrict__ Y, int RPB, int YOFF, int VOFF, int VLEN,
               int maskRows)
{
  const int b = blockIdx.y, rt = blockIdx.x;
  __shared__ float sA[64 * 33];
  __shared__ float sB[32 * 128];
  const int t = threadIdx.x;
  const int tx = t & 15, ty = t >> 4;
  const float* Pb = P + (size_t)b * 65536;
  float acc[4][8] = {};
  for (int kb = 0; kb < 256; kb += 32) {
    if constexpr (TRANSA == 0) {
      for (int l = t; l < 64 * 32; l += 256) {
        const int r = l >> 5, k = l & 31;
        sA[r*33 + k] = Pb[(size_t)(rt*64 + r) * 256 + kb + k];
      }
    } else {
      for (int l = t; l < 64 * 32; l += 256) {
        const int r = l & 63, k = l >> 6;
        sA[r*33 + k] = Pb[(size_t)(kb + k) * 256 + rt*64 + r];
      }
    }
    for (int l = t * 4; l < 32 * 128; l += 1024) {
      const int vr = kb + (l >> 7), d = l & 127;
      float4 val = {0.f, 0.f, 0.f, 0.f};
      if (vr < VLEN) val = *(const float4*)&E[((size_t)b * EPG + VOFF + vr) * 128 + d];
      *(float4*)&sB[l] = val;
    }
    __syncthreads();
    #pragma unroll
    for (int k = 0; k < 32; ++k) {
      float a[4], bb[8];
      #pragma unroll
      for (int i = 0; i < 4; ++i) a[i]  = sA[(ty*4+i)*33 + k];
      #pragma unroll
      for (int j = 0; j < 8; ++j) bb[j] = sB[k*128 + tx + 16*j];
      #pragma unroll
      for (int i = 0; i < 4; ++i)
        #pragma unroll
        for (int j = 0; j < 8; ++j) acc[i][j] += a[i] * bb[j];
    }
    __syncthreads();
  }
  #pragma unroll
  for (int i = 0; i < 4; ++i) {
    const int r = rt*64 + ty*4 + i;
    if (r >= maskRows) continue;
    float* yr = Y + ((size_t)b * RPB + YOFF + r) * 128;
    #pragma unroll
    for (int j = 0; j < 8; ++j) yr[tx + 16*j] = acc[i][j];
  }
}

// ---------------------------------------------------------------------------
// Single-pass fused sinkhorn with exp-free butterflies (round-11 proven).
// ---------------------------------------------------------------------------
__global__ __launch_bounds__(1024)
void sinkhorn_fused(float* __restrict__ S)
{
  const int b = blockIdx.x, t = threadIdx.x;
  float* Sb = S + (size_t)b * 65536;
  const int w = t >> 6, lane = t & 63;
  const int cbase = lane * 4;
  __shared__ float pm[16 * 256], ps[16 * 256];
  __shared__ float su[256], sv[256];
  if (t < 256) sv[t] = 0.f;
  __syncthreads();

  for (int it = 0; it < 10; ++it) {
    const float4 v4 = *(const float4*)&sv[cbase];
    float4 cm = {-1e30f, -1e30f, -1e30f, -1e30f};
    float4 cs = {0.f, 0.f, 0.f, 0.f};
    #pragma unroll 2
    for (int i = 0; i < 16; ++i) {
      const int r = w * 16 + i;
      const float4 s4 = *(const float4*)&Sb[(size_t)r * 256 + cbase];
      const float ax = s4.x + v4.x, ay = s4.y + v4.y;
      const float az = s4.z + v4.z, aw = s4.w + v4.w;
      float m = fmaxf(fmaxf(ax, ay), fmaxf(az, aw));
      #pragma unroll
      for (int off = 32; off; off >>= 1) m = fmaxf(m, __shfl_xor(m, off));
      float s = __expf(ax - m) + __expf(ay - m) + __expf(az - m) + __expf(aw - m);
      #pragma unroll
      for (int off = 32; off; off >>= 1) s += __shfl_xor(s, off);
      const float u = -(m + __logf(s));
      if (lane == 0) su[r] = u;
      lse_online(cm.x, cs.x, s4.x + u);
      lse_online(cm.y, cs.y, s4.y + u);
      lse_online(cm.z, cs.z, s4.z + u);
      lse_online(cm.w, cs.w, s4.w + u);
    }
    *(float4*)&pm[w * 256 + cbase] = cm;
    *(float4*)&ps[w * 256 + cbase] = cs;
    __syncthreads();
    if (t < 256) {
      float m = pm[t];
      #pragma unroll
      for (int k = 1; k < 16; ++k) m = fmaxf(m, pm[k * 256 + t]);
      float s = 0.f;
      #pragma unroll
      for (int k = 0; k < 16; ++k) s += ps[k * 256 + t] * __expf(pm[k * 256 + t] - m);
      sv[t] = -(m + __logf(s));
    }
    __syncthreads();
  }
  for (int i = t; i < 16384; i += 1024) {
    const int row = i >> 6, c4 = (i & 63) * 4;
    float4 s4 = *(float4*)&Sb[(size_t)row * 256 + c4];
    const float uu = su[row];
    const float4 v4 = *(const float4*)&sv[c4];
    s4.x = __expf(s4.x + uu + v4.x);
    s4.y = __expf(s4.y + uu + v4.y);
    s4.z = __expf(s4.z + uu + v4.z);
    s4.w = __expf(s4.w + uu + v4.w);
    *(float4*)&Sb[(size_t)row * 256 + c4] = s4;
  }
}

// ---------------------------------------------------------------------------
// score[b] = -sum_{m<256,d} | (m<EQ ? e_q[m,d] : 0) - pc[m,d] |
// ---------------------------------------------------------------------------
__global__ __launch_bounds__(256)
void escore_kernel(const float* __restrict__ e, const float* __restrict__ pc,
                   float* __restrict__ out)
{
  const int b = blockIdx.x, t = threadIdx.x;
  float acc = 0.f;
  for (int i4 = t; i4 < 8192; i4 += 256) {
    const int flat = i4 * 4;
    const int m = flat >> 7, d = flat & 127;
    float4 p = *(const float4*)&pc[((size_t)b * 256 + m) * 128 + d];
    float4 q = {0.f, 0.f, 0.f, 0.f};
    if (m < EQ_) q = *(const float4*)&e[((size_t)b * EPG + m) * 128 + d];
    acc += fabsf(q.x - p.x) + fabsf(q.y - p.y) + fabsf(q.z - p.z) + fabsf(q.w - p.w);
  }
  __shared__ float red[256];
  red[t] = acc; __syncthreads();
  for (int s2 = 128; s2 > 0; s2 >>= 1) { if (t < s2) red[t] += red[t + s2]; __syncthreads(); }
  if (t == 0) out[b] = -red[0];
}

// ---------------------------------------------------------------------------
extern "C" void kernel_launch(void* const* d_in, const int* in_sizes, int n_in,
                              void* d_out, int out_size, void* d_ws, size_t ws_size,
                              hipStream_t stream)
{
  const float* node_features = (const float*)d_in[0];
  const float* edge_features = (const float*)d_in[1];
  const int*   from_idx      = (const int*)d_in[2];
  const int*   to_idx        = (const int*)d_in[3];
  const float* enc_node_W = (const float*)d_in[4];
  const float* enc_node_b = (const float*)d_in[5];
  const float* enc_edge_W = (const float*)d_in[6];
  const float* enc_edge_b = (const float*)d_in[7];
  const float* msg_W1 = (const float*)d_in[8];
  const float* msg_b1 = (const float*)d_in[9];
  const float* msg_W2 = (const float*)d_in[10];
  const float* msg_b2 = (const float*)d_in[11];
  const float* upd_W1 = (const float*)d_in[12];
  const float* upd_b1 = (const float*)d_in[13];
  const float* upd_W2 = (const float*)d_in[14];
  const float* upd_b2 = (const float*)d_in[15];
  const float* int_W1 = (const float*)d_in[16];
  const float* int_b1 = (const float*)d_in[17];
  const float* int_W2 = (const float*)d_in[18];
  const float* int_b2 = (const float*)d_in[19];
  const float* sink_W1 = (const float*)d_in[20];
  const float* sink_b1 = (const float*)d_in[21];
  const float* sink_W2 = (const float*)d_in[22];
  const float* sink_b2 = (const float*)d_in[23];
  float* out = (float*)d_out;

  // ~224 MB layout (proven). h bf16; aggF/aggB bf16; mf/mb alias e's dead window.
  float* wsf = (float*)d_ws;
  float* hreg = wsf;                              // region: NN*64 f32-sized
  float* e   = hreg + (size_t)NN * 64;            // NE*128 f32
  float* shr = e + (size_t)NE * 128;              // NE*128 f32 (inter | agg bf16 | fq+fc | pc)
  float* S   = shr + (size_t)NE * 128;            // BATCH*65536 f32
  u16* comb  = (u16*)(S + (size_t)BATCH * 65536); // NE*128 bf16
  u16* wi1 = comb + (size_t)NE * 128;             // 256x256
  u16* wi2 = wi1 + 65536;                         // 128x256
  u16* wm1 = wi2 + 32768;                         // 256x256
  u16* wm2 = wm1 + 65536;                         // 128x256
  u16* wu1 = wm2 + 32768;                         // 128x320
  u16* wu2 = wu1 + 40960;                         // 64x128

  u16* hb  = (u16*)hreg;                          // NN*64 bf16 node states
  u16* mfb = (u16*)e;                             // aliases e (dead window)
  u16* mbb = mfb + (size_t)NE * 128;

  u16* aggFb = (u16*)shr;                         // NN*128 bf16
  u16* aggBb = aggFb + (size_t)NN * 128;
  float* inter = shr;                             // EPG-row layout (f32)
  float* fq    = shr;
  float* fc    = shr + (size_t)BATCH * 16384;

  // weights -> bf16, transposed [N][K]
  wconv<<<256, 256, 0, stream>>>(int_W1, wi1, 256, 256);
  wconv<<<128, 256, 0, stream>>>(int_W2, wi2, 256, 128);
  wconv<<<256, 256, 0, stream>>>(msg_W1, wm1, 256, 256);
  wconv<<<128, 256, 0, stream>>>(msg_W2, wm2, 256, 128);
  wconv<<<160, 256, 0, stream>>>(upd_W1, wu1, 320, 128);
  wconv<<< 32, 256, 0, stream>>>(upd_W2, wu2, 128, 64);

  for (int ts = 0; ts < 2; ++ts) {
    // encoders (reset hb, e)
    fused_mlp<32,64,64,0,1,1><<<NN/32, 256, 0, stream>>>(
        node_features, nullptr, enc_node_W, enc_node_b, nullptr, nullptr,
        nullptr, hb, -1);
    fused_mlp<32,128,128,0,1,0><<<NE/32, 256, 0, stream>>>(
        edge_features, nullptr, enc_edge_W, enc_edge_b, nullptr, nullptr,
        e, nullptr, -1);

    for (int p = 0; p < 3; ++p) {
      // comb = intMLP([e, inter]) -> bf16   (inter==0 for ts0 and ts1/p0)
      const float* interArg = (ts == 1 && p > 0) ? inter : nullptr;
      mlp_mfma<256,256,128,4,0,1,8><<<NE/32, 512, 0, stream>>>(
          e, interArg, nullptr, nullptr, nullptr, nullptr,
          wi1, int_b1, wi2, int_b2, nullptr, comb, nullptr);
      // messages on old h -> mf, mb (bf16, in e's dead storage), both dirs
      mlp_mfma<256,256,128,1,1,2,8><<<NE/32, 512, 0, stream>>>(
          hb, nullptr, nullptr, comb, from_idx, to_idx,
          wm1, msg_b1, wm2, msg_b2, nullptr, mfb, mbb);
      // pair-local segment sums (LDS), both dirs as blocks -> bf16 agg
      scatter_agg<<<BATCH*2, 512, 0, stream>>>(mfb, mbb, from_idx, to_idx, aggFb, aggBb);
      // node update (in place, bf16)
      mlp_mfma<320,128,64,3,0,1,4><<<NN/32, 256, 0, stream>>>(
          hb, aggFb, aggBb, nullptr, nullptr, nullptr,
          wu1, upd_b1, wu2, upd_b2, nullptr, hb, nullptr);
      // e = mf2 + mb2 with updated h (dual-direction sum; overwrites mf/mb)
      mlp_mfma<256,256,128,1,1,0,8><<<NE/32, 512, 0, stream>>>(
          hb, nullptr, nullptr, comb, from_idx, to_idx,
          wm1, msg_b1, wm2, msg_b2, e, nullptr, nullptr);
      // interaction features from last time step's transport plan
      if (ts == 1 && p < 2) {
        gemm_plan<0><<<dim3(4, BATCH), 256, 0, stream>>>(
            S, e, inter, EPG, 0,   EQ_, EC_, EQ_);
        gemm_plan<1><<<dim3(4, BATCH), 256, 0, stream>>>(
            S, e, inter, EPG, EQ_, 0,   EQ_, EC_);
      }
    }
    // sinkhorn features + plan
    fused_mlp<128,64,64,5,0,0><<<BATCH*8, 256, 0, stream>>>(
        nullptr, e, sink_W1, sink_b1, sink_W2, sink_b2, fq, nullptr, EQ_);
    fused_mlp<128,64,64,6,0,0><<<BATCH*8, 256, 0, stream>>>(
        nullptr, e, sink_W1, sink_b1, sink_W2, sink_b2, fc, nullptr, EC_);
    gemm_nt_scale<<<dim3(4,4,BATCH), 256, 0, stream>>>(fq, fc, S, 10.0f);
    sinkhorn_fused<<<BATCH, 1024, 0, stream>>>(S);   // S := plan
  }

  // final score
  gemm_plan<0><<<dim3(4, BATCH), 256, 0, stream>>>(S, e, shr, 256, 0, EQ_, EC_, 256);
  escore_kernel<<<BATCH, 256, 0, stream>>>(e, shr, out);
}